// Round 5
// baseline (22473.009 us; speedup 1.0000x reference)
//
#include <hip/hip_runtime.h>
#include <hip/hip_bf16.h>
#include <math.h>

// ---------------------------------------------------------------------------
// RGN model: T=700 B=32 H=800 EMB=32 EVO=21 A=60
// f32 in / f32 out; internal bf16 MFMA.
// Persistent biLSTM: weights L2-resident; h exchange via device-coherent
// (sc0|sc1) ops at IF$. Async global->LDS staging (one vmcnt wait/step),
// flag-array barrier with split fwd/bwd domains.
// ---------------------------------------------------------------------------

typedef unsigned int u32;
typedef __bf16 bf16x8 __attribute__((ext_vector_type(8)));
typedef float  f32x4  __attribute__((ext_vector_type(4)));

#define TT 700
#define BT 32
#define HROW 1600
#define NWG 100
#define LDS_BYTES (300 * 512)   // 300 k-groups x [32 batch][8 bf16]

__device__ __forceinline__ f32x4 mfma16(bf16x8 a, bf16x8 b, f32x4 c) {
  return __builtin_amdgcn_mfma_f32_16x16x32_bf16(a, b, c, 0, 0, 0);
}
__device__ __forceinline__ float sigf(float x) { return 1.f / (1.f + __expf(-x)); }

#define ALOAD(p)    __hip_atomic_load((p), __ATOMIC_RELAXED, __HIP_MEMORY_SCOPE_AGENT)
#define ASTORE(p,v) __hip_atomic_store((p), (v), __ATOMIC_RELAXED, __HIP_MEMORY_SCOPE_AGENT)

// async 16B global->LDS; AUX: 0 = cached, 17 = sc0|sc1 device-coherent
template <unsigned AUX>
__device__ __forceinline__ void gld_lds16(const __bf16* g, __bf16* l) {
  __builtin_amdgcn_global_load_lds(
      (const __attribute__((address_space(1))) unsigned int*)g,
      (__attribute__((address_space(3))) unsigned int*)l, 16, 0, AUX);
}

// ---------------- pack / init kernels ----------------
__global__ void cvt_f32_bf16_kernel(const float* __restrict__ src,
                                    __bf16* __restrict__ dst, int n) {
  for (int i = blockIdx.x * 256 + threadIdx.x; i < n; i += gridDim.x * 256)
    dst[i] = (__bf16)src[i];
}

__global__ void pack_wx0_kernel(const float* Wih0f, const float* Wih0b, __bf16* wx0) {
  int idx = blockIdx.x * 256 + threadIdx.x;      // 2*3200*64 = 409600 exact
  if (idx >= 2 * 3200 * 64) return;
  int d = idx / (3200 * 64);
  int r = (idx / 64) % 3200;
  int k = idx % 64;
  const float* W = d ? Wih0b : Wih0f;
  wx0[idx] = (k < 53) ? (__bf16)W[(size_t)r * 53 + k] : (__bf16)0.f;
}

__global__ void pack_fc_kernel(const float* fcW, __bf16* wfc) {
  int idx = blockIdx.x * 256 + threadIdx.x;
  if (idx >= 64 * 1664) return;
  int a = idx / 1664, k = idx % 1664;
  __bf16 v = (__bf16)0.f;
  if (a < 60 && k < 1653) v = (__bf16)fcW[(size_t)a * 1653 + k];
  wfc[idx] = v;
}

__global__ void xpad_kernel(const int* primary, const float* evo,
                            const float* emb, __bf16* xpad) {
  int idx = blockIdx.x * 256 + threadIdx.x;   // 700*32*64 exact
  int t = idx >> 11;
  int b = (idx >> 6) & 31;
  int k = idx & 63;
  __bf16 v = (__bf16)0.f;
  if (k < 32)      v = (__bf16)emb[primary[t * 32 + b] * 32 + k];
  else if (k < 53) v = (__bf16)evo[((size_t)t * 32 + b) * 21 + (k - 32)];
  xpad[idx] = v;
}

__global__ void small_init_kernel(__bf16* zerobuf, u32* flags,
                                  float* sinA, float* cosA, const float* alpha) {
  int idx = blockIdx.x * 256 + threadIdx.x;
  if (idx < 32 * 1600) zerobuf[idx] = (__bf16)0.f;
  if (idx < 3200) flags[idx] = 0u;
  int j = idx - 32 * 1600;
  if (j >= 0 && j < 192) {
    if (j < 180) {
      float v = alpha[j];
      sinA[j] = sinf(v);
      cosA[j] = cosf(v);
    } else { sinA[j] = 0.f; cosA[j] = 0.f; }
  }
}

// ---------------- persistent biLSTM ----------------
struct LstmArgs {
  const __bf16 *xpad, *wx0, *zero;
  const __bf16 *wh0, *wh1, *wi1;     // packed bf16: [dir][3200][800/800/1600]
  __bf16 *h0, *h1;
  const float *b0f, *b0b, *b1f, *b1b;
  u32* flags;                        // 100 flags, 128B apart
};

// Flag-array barrier: each WG publishes gen to its own cacheline; wave 0
// ballot-spins on the domain's flags (parallel loads, ~1 IF$ round trip).
__device__ __forceinline__ void flag_barrier(u32* flags, unsigned gen,
                                             int base, int count) {
  const int tid = threadIdx.x;
  if (tid < 64) {
    if (tid == 0) ASTORE(flags + (size_t)blockIdx.x * 32, gen);
    for (;;) {
      bool ok = true;
      for (int j = tid; j < count; j += 64)
        ok = ok && (ALOAD(flags + (size_t)(base + j) * 32) >= gen);
      if (__popcll(__ballot(ok)) == 64) break;
      __builtin_amdgcn_s_sleep(1);
    }
  }
  __syncthreads();
}

template <int LAYER>
__device__ __forceinline__ void run_layer(
    const __bf16* __restrict__ Whh,   // (3200,800) bf16, dir-selected
    const __bf16* __restrict__ Wx,    // L0: wx0 dir (3200,64); L1: wi1 dir (3200,1600)
    const float*  __restrict__ bias,
    const __bf16* __restrict__ aux,   // L1 only: h0 [t][b][1600]
    const __bf16* __restrict__ hself, // own-layer h (prev-step source)
    __bf16* __restrict__ hdst,
    const __bf16* __restrict__ zerobuf,
    const __bf16* __restrict__ xpad,
    u32* flags, unsigned& gen, int d, int u0, __bf16* u2) {
  const int tid  = threadIdx.x;
  const int w    = tid >> 6, l = tid & 63;
  const int nidx = l & 15, q = l >> 4;
  const int bL   = l & 31, gl = l >> 5;
  const int dcol = d * 800;
  const int row  = w * 800 + u0 + nidx;          // gate row in [0,3200)
  const float bias_n = bias[row];
  const __bf16* whh_row = Whh + (size_t)row * 800 + q * 8;
  const __bf16* wx_row  = LAYER ? (Wx + (size_t)row * 1600 + q * 8)
                                : (Wx + (size_t)row * 64 + q * 8);
  const int bb = tid >> 3, up = tid & 7;
  float* g_lds = (float*)u2;   // overlays groups 0..15 after MFMAs complete
  float cA = 0.f, cB = 0.f;

#pragma unroll 1
  for (int s = 0; s < TT; ++s) {
    const int tt = d ? (TT - 1 - s) : s;
    const __bf16* hprev =
        (s == 0) ? zerobuf
                 : (hself + (size_t)(d ? tt + 1 : tt - 1) * (BT * HROW));

    // L0 x-tail: issue load first (oldest in vmcnt queue)
    bf16x8 xv;
    if (LAYER == 0)
      xv = *(const bf16x8*)(xpad + ((size_t)tt * BT + bL) * 64 + (tid >> 5) * 8);

    // h-prev: async device-coherent global->LDS, groups 0..99
    const __bf16* hsrc = hprev + (size_t)bL * HROW + dcol;
#pragma unroll
    for (int i = 0; i < 12; ++i)
      gld_lds16<17>(hsrc + (i * 8 + w * 2 + gl) * 8, u2 + (i * 8 + w * 2) * 256);
    if (w < 2)
      gld_lds16<17>(hsrc + (96 + w * 2 + gl) * 8, u2 + (96 + w * 2) * 256);

    if (LAYER == 0) {
      // x-tail -> groups 100..107
      *(bf16x8*)(u2 + (size_t)(100 + (tid >> 5)) * 256 + bL * 8) = xv;
    } else {
      // aux = h0[t] (stable in phase 2): async cached -> groups 100..299
#pragma unroll
      for (int p = 1; p <= 2; ++p) {
        const __bf16* asrc = aux + ((size_t)tt * BT + bL) * HROW + (p - 1) * 800;
#pragma unroll
        for (int i = 0; i < 12; ++i)
          gld_lds16<0>(asrc + (i * 8 + w * 2 + gl) * 8,
                       u2 + (size_t)(100 * p + i * 8 + w * 2) * 256);
        if (w < 2)
          gld_lds16<0>(asrc + (96 + w * 2 + gl) * 8,
                       u2 + (size_t)(100 * p + 96 + w * 2) * 256);
      }
    }

    asm volatile("s_waitcnt vmcnt(0)" ::: "memory");
    __syncthreads();

    // ---- MFMA: u2 layout [group][b][8]; A-frag = ds_read_b128, 2-way free ----
    f32x4 acc0 = {0.f, 0.f, 0.f, 0.f}, acc1 = {0.f, 0.f, 0.f, 0.f};
    constexpr int NSL = LAYER ? 25 : 27;
#pragma unroll
    for (int sl = 0; sl < NSL; ++sl) {
      const __bf16* wsrc = (LAYER == 0 && sl >= 25) ? (wx_row + (sl - 25) * 32)
                                                    : (whh_row + sl * 32);
      bf16x8 bfr = *(const bf16x8*)wsrc;
      const __bf16* ab = u2 + (size_t)(sl * 4 + q) * 256 + nidx * 8;
      bf16x8 a0 = *(const bf16x8*)ab;
      bf16x8 a1 = *(const bf16x8*)(ab + 128);
      acc0 = mfma16(a0, bfr, acc0);
      acc1 = mfma16(a1, bfr, acc1);
    }
    if (LAYER) {
#pragma unroll
      for (int p = 1; p <= 2; ++p) {
#pragma unroll
        for (int sl = 0; sl < 25; ++sl) {
          bf16x8 bfr = *(const bf16x8*)(wx_row + (p - 1) * 800 + sl * 32);
          const __bf16* ab = u2 + (size_t)(100 * p + sl * 4 + q) * 256 + nidx * 8;
          bf16x8 a0 = *(const bf16x8*)ab;
          bf16x8 a1 = *(const bf16x8*)(ab + 128);
          acc0 = mfma16(a0, bfr, acc0);
          acc1 = mfma16(a1, bfr, acc1);
        }
      }
    }
    __syncthreads();

    // ---- gate exchange (C layout: col=nidx=unit, row=q*4+r=batch) ----
#pragma unroll
    for (int r = 0; r < 4; ++r) {
      g_lds[w * 512 + (q * 4 + r) * 16 + nidx]      = acc0[r] + bias_n;
      g_lds[w * 512 + (16 + q * 4 + r) * 16 + nidx] = acc1[r] + bias_n;
    }
    __syncthreads();

    // ---- nonlinearity: thread owns (b=bb, units u0+2up, u0+2up+1) ----
    {
      const int uA = 2 * up, uB = uA + 1;
      float iA = g_lds[0 * 512 + bb * 16 + uA], fA = g_lds[1 * 512 + bb * 16 + uA];
      float gA = g_lds[2 * 512 + bb * 16 + uA], oA = g_lds[3 * 512 + bb * 16 + uA];
      cA = sigf(fA) * cA + sigf(iA) * tanhf(gA);
      float hA = sigf(oA) * tanhf(cA);
      float iB = g_lds[0 * 512 + bb * 16 + uB], fB = g_lds[1 * 512 + bb * 16 + uB];
      float gB = g_lds[2 * 512 + bb * 16 + uB], oB = g_lds[3 * 512 + bb * 16 + uB];
      cB = sigf(fB) * cB + sigf(iB) * tanhf(gB);
      float hB = sigf(oB) * tanhf(cB);
      union { u32 u; __bf16 h2[2]; } pk;
      pk.h2[0] = (__bf16)hA;
      pk.h2[1] = (__bf16)hB;
      ASTORE((u32*)(hdst + ((size_t)tt * BT + bb) * HROW + dcol + u0 + uA), pk.u);
    }

    const bool lastL1 = (LAYER == 1) && (s == TT - 1);
    if (!lastL1) {
      asm volatile("s_waitcnt vmcnt(0)" ::: "memory");  // h stores at IF$
      __syncthreads();
      ++gen;
      const bool full = (LAYER == 0) && (s == TT - 1);  // phase transition
      flag_barrier(flags, gen, full ? 0 : d * 50, full ? 100 : 50);
    }
  }
}

__global__ __launch_bounds__(256, 1) void lstm_kernel(LstmArgs A) {
  extern __shared__ __bf16 u2[];   // 153,600 B
  const int wg = blockIdx.x;
  const int d  = wg / 50;
  const int u0 = (wg % 50) * 16;
  unsigned gen = 0;
  run_layer<0>(A.wh0 + (size_t)d * 3200 * 800, A.wx0 + (size_t)d * 3200 * 64,
               d ? A.b0b : A.b0f, nullptr, A.h0, A.h0, A.zero, A.xpad,
               A.flags, gen, d, u0, u2);
  run_layer<1>(A.wh1 + (size_t)d * 3200 * 800, A.wi1 + (size_t)d * 3200 * 1600,
               d ? A.b1b : A.b1f, A.h0, A.h1, A.h1, A.zero, A.xpad,
               A.flags, gen, d, u0, u2);
}

// ---------------- FC + softmax + dihedral -> points ----------------
__global__ __launch_bounds__(256) void fc_kernel(
    const __bf16* __restrict__ h1, const __bf16* __restrict__ xpad,
    const __bf16* __restrict__ wfc, const float* __restrict__ fcb,
    const float* __restrict__ sinA, const float* __restrict__ cosA,
    float* __restrict__ pts) {
  __shared__ float lg[32 * 64];
  const int t = blockIdx.x, tid = threadIdx.x;
  const int wave = tid >> 6, lane = tid & 63, nidx = lane & 15, q = lane >> 4;
  const int a_col = wave * 16 + nidx;
  const __bf16* wrow = wfc + (size_t)a_col * 1664 + q * 8;
  const __bf16* h1row = h1 + (size_t)t * BT * HROW;
  const __bf16* xrow  = xpad + (size_t)t * BT * 64;
  f32x4 acc0 = {0.f, 0.f, 0.f, 0.f}, acc1 = {0.f, 0.f, 0.f, 0.f};
#pragma unroll
  for (int sl = 0; sl < 52; ++sl) {
    const int k = sl * 32 + q * 8;
    bf16x8 a0, a1;
    if (sl < 50) {
      a0 = *(const bf16x8*)(h1row + (size_t)nidx * HROW + k);
      a1 = *(const bf16x8*)(h1row + (size_t)(16 + nidx) * HROW + k);
    } else {
      a0 = *(const bf16x8*)(xrow + nidx * 64 + (k - 1600));
      a1 = *(const bf16x8*)(xrow + (16 + nidx) * 64 + (k - 1600));
    }
    bf16x8 bfr = *(const bf16x8*)(wrow + sl * 32);
    acc0 = mfma16(a0, bfr, acc0);
    acc1 = mfma16(a1, bfr, acc1);
  }
  const float bn = (a_col < 60) ? fcb[a_col] : -1e30f;
#pragma unroll
  for (int r = 0; r < 4; ++r) {
    lg[(q * 4 + r) * 64 + a_col]      = acc0[r] + bn;
    lg[(16 + q * 4 + r) * 64 + a_col] = acc1[r] + bn;
  }
  __syncthreads();

  const int b = tid >> 3, j = tid & 7;
  float v[8];
  float m = -1e30f;
#pragma unroll
  for (int k2 = 0; k2 < 8; ++k2) {
    v[k2] = lg[b * 64 + j + 8 * k2];
    m = fmaxf(m, v[k2]);
  }
  m = fmaxf(m, __shfl_xor(m, 1, 8));
  m = fmaxf(m, __shfl_xor(m, 2, 8));
  m = fmaxf(m, __shfl_xor(m, 4, 8));
  float s = 0.f;
#pragma unroll
  for (int k2 = 0; k2 < 8; ++k2) { v[k2] = __expf(v[k2] - m); s += v[k2]; }
  s += __shfl_xor(s, 1, 8);
  s += __shfl_xor(s, 2, 8);
  s += __shfl_xor(s, 4, 8);
  const float inv = 1.f / s;
  float ps[3] = {0.f, 0.f, 0.f}, pc[3] = {0.f, 0.f, 0.f};
#pragma unroll
  for (int k2 = 0; k2 < 8; ++k2) {
    const int a = j + 8 * k2;
    const float p = v[k2] * inv;
#pragma unroll
    for (int c = 0; c < 3; ++c) {
      ps[c] += p * sinA[a * 3 + c];
      pc[c] += p * cosA[a * 3 + c];
    }
  }
#pragma unroll
  for (int c = 0; c < 3; ++c) {
    ps[c] += __shfl_xor(ps[c], 1, 8);
    ps[c] += __shfl_xor(ps[c], 2, 8);
    ps[c] += __shfl_xor(ps[c], 4, 8);
    pc[c] += __shfl_xor(pc[c], 1, 8);
    pc[c] += __shfl_xor(pc[c], 2, 8);
    pc[c] += __shfl_xor(pc[c], 4, 8);
  }
  if (j == 0) {
    const float BL[3] = {145.801f, 152.326f, 132.868f};
    const float BA[3] = {2.124f, 1.941f, 2.028f};
#pragma unroll
    for (int c = 0; c < 3; ++c) {
      const float ang = 3.14159265358979323846f - BA[c];
      const float rct = BL[c] * cosf(ang), rst = BL[c] * sinf(ang);
      const float dih = atan2f(ps[c], pc[c]);
      float* o = pts + ((size_t)(3 * t + c) * BT + b) * 3;
      o[0] = rct;
      o[1] = cosf(dih) * rst;
      o[2] = sinf(dih) * rst;
    }
  }
}

// ---------------- sequential NeRF extension ----------------
__global__ void nerf_kernel(const float* __restrict__ pts, float* __restrict__ out) {
  const int b = threadIdx.x;
  if (b >= 32) return;
  float ax = -0.70710678f, ay = 1.22474487f, az = 0.f;
  float bx = -1.41421356f, by = 0.f, bz = 0.f;
  float cx = 0.f, cy = 0.f, cz = 0.f;
#pragma unroll 4
  for (int i = 0; i < 3 * TT; ++i) {
    const float* p = pts + ((size_t)i * BT + b) * 3;
    const float p0 = p[0], p1 = p[1], p2 = p[2];
    float ux = cx - bx, uy = cy - by, uz = cz - bz;
    const float ri = rsqrtf(ux * ux + uy * uy + uz * uz + 1e-12f);
    ux *= ri; uy *= ri; uz *= ri;
    const float wx = bx - ax, wy = by - ay, wz = bz - az;
    float nx = wy * uz - wz * uy, ny = wz * ux - wx * uz, nz = wx * uy - wy * ux;
    const float rn = rsqrtf(nx * nx + ny * ny + nz * nz + 1e-12f);
    nx *= rn; ny *= rn; nz *= rn;
    const float mx = ny * uz - nz * uy, my = nz * ux - nx * uz, mz = nx * uy - ny * ux;
    const float ox = cx + p0 * ux + p1 * mx + p2 * nx;
    const float oy = cy + p0 * uy + p1 * my + p2 * ny;
    const float oz = cz + p0 * uz + p1 * mz + p2 * nz;
    out[((size_t)i * BT + b) * 3 + 0] = ox;
    out[((size_t)i * BT + b) * 3 + 1] = oy;
    out[((size_t)i * BT + b) * 3 + 2] = oz;
    ax = bx; ay = by; az = bz;
    bx = cx; by = cy; bz = cz;
    cx = ox; cy = oy; cz = oz;
  }
}

// ---------------- launch ----------------
extern "C" void kernel_launch(void* const* d_in, const int* in_sizes, int n_in,
                              void* d_out, int out_size, void* d_ws, size_t ws_size,
                              hipStream_t stream) {
  (void)in_sizes; (void)n_in; (void)out_size;
  const int*   primary = (const int*)d_in[0];
  const float* evo     = (const float*)d_in[1];
  const float* emb     = (const float*)d_in[3];
  const float* Wih0f   = (const float*)d_in[4];
  const float* Whh0f   = (const float*)d_in[5];
  const float* b0f     = (const float*)d_in[6];
  const float* Wih0b   = (const float*)d_in[7];
  const float* Whh0b   = (const float*)d_in[8];
  const float* b0b     = (const float*)d_in[9];
  const float* Wih1f   = (const float*)d_in[10];
  const float* Whh1f   = (const float*)d_in[11];
  const float* b1f     = (const float*)d_in[12];
  const float* Wih1b   = (const float*)d_in[13];
  const float* Whh1b   = (const float*)d_in[14];
  const float* b1b     = (const float*)d_in[15];
  const float* fcW     = (const float*)d_in[16];
  const float* fcb     = (const float*)d_in[17];
  const float* alpha   = (const float*)d_in[18];

  char* ws = (char*)d_ws;
  size_t off = 0;
  auto take = [&](size_t n) -> void* {
    void* p = ws + off;
    off += (n + 511) & ~(size_t)511;
    return p;
  };
  __bf16* xpad = (__bf16*)take((size_t)TT * BT * 64 * 2);      // 2.87 MB
  __bf16* zb   = (__bf16*)take((size_t)BT * HROW * 2);         // 102 KB
  __bf16* wx0  = (__bf16*)take((size_t)2 * 3200 * 64 * 2);     // 819 KB
  __bf16* wfc  = (__bf16*)take((size_t)64 * 1664 * 2);         // 213 KB
  float*  sinA = (float*)take(192 * 4);
  float*  cosA = (float*)take(192 * 4);
  float*  pts  = (float*)take((size_t)3 * TT * BT * 3 * 4);    // 806 KB
  u32*    flags= (u32*)take(3200 * 4);                          // 12.8 KB
  __bf16* wh0  = (__bf16*)take((size_t)2 * 3200 * 800 * 2);    // 10.24 MB
  __bf16* wh1  = (__bf16*)take((size_t)2 * 3200 * 800 * 2);    // 10.24 MB
  __bf16* wi1  = (__bf16*)take((size_t)2 * 3200 * 1600 * 2);   // 20.48 MB
  __bf16* h0   = (__bf16*)take((size_t)TT * BT * HROW * 2);    // 71.68 MB
  __bf16* h1   = (__bf16*)take((size_t)TT * BT * HROW * 2);    // 71.68 MB
  if (off > ws_size) return;  // failure signature: absmax == max|ref| == 233472

  static int lds_cfg = 0;
  if (!lds_cfg) {   // idempotent attribute set (same value every call)
    hipFuncSetAttribute((const void*)lstm_kernel,
                        hipFuncAttributeMaxDynamicSharedMemorySize, LDS_BYTES);
    lds_cfg = 1;
  }

  const int NW = 3200 * 800;
  const int NI = 3200 * 1600;
  cvt_f32_bf16_kernel<<<2048, 256, 0, stream>>>(Whh0f, wh0, NW);
  cvt_f32_bf16_kernel<<<2048, 256, 0, stream>>>(Whh0b, wh0 + NW, NW);
  cvt_f32_bf16_kernel<<<2048, 256, 0, stream>>>(Whh1f, wh1, NW);
  cvt_f32_bf16_kernel<<<2048, 256, 0, stream>>>(Whh1b, wh1 + NW, NW);
  cvt_f32_bf16_kernel<<<2048, 256, 0, stream>>>(Wih1f, wi1, NI);
  cvt_f32_bf16_kernel<<<2048, 256, 0, stream>>>(Wih1b, wi1 + NI, NI);
  pack_wx0_kernel<<<1600, 256, 0, stream>>>(Wih0f, Wih0b, wx0);
  pack_fc_kernel<<<(64 * 1664 + 255) / 256, 256, 0, stream>>>(fcW, wfc);
  xpad_kernel<<<(TT * BT * 64) / 256, 256, 0, stream>>>(primary, evo, emb, xpad);
  small_init_kernel<<<202, 256, 0, stream>>>(zb, flags, sinA, cosA, alpha);

  LstmArgs a;
  a.xpad = xpad; a.wx0 = wx0; a.zero = zb;
  a.wh0 = wh0; a.wh1 = wh1; a.wi1 = wi1;
  a.h0 = h0; a.h1 = h1;
  a.b0f = b0f; a.b0b = b0b; a.b1f = b1f; a.b1b = b1b;
  a.flags = flags;
  lstm_kernel<<<NWG, 256, LDS_BYTES, stream>>>(a);

  fc_kernel<<<TT, 256, 0, stream>>>(h1, xpad, wfc, fcb, sinA, cosA, pts);
  nerf_kernel<<<1, 64, 0, stream>>>(pts, (float*)d_out);
}

// Round 6
// 21113.264 us; speedup vs baseline: 1.0644x; 1.0644x over previous
//
#include <hip/hip_runtime.h>
#include <hip/hip_bf16.h>
#include <math.h>

// ---------------------------------------------------------------------------
// RGN model: T=700 B=32 H=800 EMB=32 EVO=21 A=60
// f32 in / f32 out; internal bf16 MFMA.
// Persistent biLSTM: L0 weights LDS-resident; L1 weights L2-resident.
// h exchange: write-through agent atomics (stores) + cached reads (correct
// because every h address is written once, then read only after a barrier,
// and dispatch start invalidates L2). Flag-array barrier, fwd/bwd domains.
// ---------------------------------------------------------------------------

typedef unsigned int u32;
typedef __bf16 bf16x8 __attribute__((ext_vector_type(8)));
typedef float  f32x4  __attribute__((ext_vector_type(4)));

#define TT 700
#define BT 32
#define HROW 1600
#define NWG 100
#define LDS_BYTES 157696   // 108 staging groups (55296 B) + L0 weights (102400 B)

__device__ __forceinline__ f32x4 mfma16(bf16x8 a, bf16x8 b, f32x4 c) {
  return __builtin_amdgcn_mfma_f32_16x16x32_bf16(a, b, c, 0, 0, 0);
}
__device__ __forceinline__ float sigf(float x) { return 1.f / (1.f + __expf(-x)); }

#define ALOAD(p)    __hip_atomic_load((p), __ATOMIC_RELAXED, __HIP_MEMORY_SCOPE_AGENT)
#define ASTORE(p,v) __hip_atomic_store((p), (v), __ATOMIC_RELAXED, __HIP_MEMORY_SCOPE_AGENT)

// async 16B global->LDS, cached path (L2-allowed)
__device__ __forceinline__ void gld_lds16(const __bf16* g, __bf16* l) {
  __builtin_amdgcn_global_load_lds(
      (const __attribute__((address_space(1))) unsigned int*)g,
      (__attribute__((address_space(3))) unsigned int*)l, 16, 0, 0);
}

// ---------------- pack / init kernels ----------------
__global__ void cvt_f32_bf16_kernel(const float* __restrict__ src,
                                    __bf16* __restrict__ dst, int n) {
  for (int i = blockIdx.x * 256 + threadIdx.x; i < n; i += gridDim.x * 256)
    dst[i] = (__bf16)src[i];
}

__global__ void pack_wx0_kernel(const float* Wih0f, const float* Wih0b, __bf16* wx0) {
  int idx = blockIdx.x * 256 + threadIdx.x;      // 2*3200*64 = 409600 exact
  if (idx >= 2 * 3200 * 64) return;
  int d = idx / (3200 * 64);
  int r = (idx / 64) % 3200;
  int k = idx % 64;
  const float* W = d ? Wih0b : Wih0f;
  wx0[idx] = (k < 53) ? (__bf16)W[(size_t)r * 53 + k] : (__bf16)0.f;
}

__global__ void pack_fc_kernel(const float* fcW, __bf16* wfc) {
  int idx = blockIdx.x * 256 + threadIdx.x;
  if (idx >= 64 * 1664) return;
  int a = idx / 1664, k = idx % 1664;
  __bf16 v = (__bf16)0.f;
  if (a < 60 && k < 1653) v = (__bf16)fcW[(size_t)a * 1653 + k];
  wfc[idx] = v;
}

__global__ void xpad_kernel(const int* primary, const float* evo,
                            const float* emb, __bf16* xpad) {
  int idx = blockIdx.x * 256 + threadIdx.x;   // 700*32*64 exact
  int t = idx >> 11;
  int b = (idx >> 6) & 31;
  int k = idx & 63;
  __bf16 v = (__bf16)0.f;
  if (k < 32)      v = (__bf16)emb[primary[t * 32 + b] * 32 + k];
  else if (k < 53) v = (__bf16)evo[((size_t)t * 32 + b) * 21 + (k - 32)];
  xpad[idx] = v;
}

__global__ void small_init_kernel(__bf16* zerobuf, u32* flags,
                                  float* sinA, float* cosA, const float* alpha) {
  int idx = blockIdx.x * 256 + threadIdx.x;
  if (idx < 32 * 1600) zerobuf[idx] = (__bf16)0.f;
  if (idx < 3200) flags[idx] = 0u;
  int j = idx - 32 * 1600;
  if (j >= 0 && j < 192) {
    if (j < 180) {
      float v = alpha[j];
      sinA[j] = sinf(v);
      cosA[j] = cosf(v);
    } else { sinA[j] = 0.f; cosA[j] = 0.f; }
  }
}

// ---------------- persistent biLSTM ----------------
struct LstmArgs {
  const __bf16 *xpad, *wx0, *zero;
  const __bf16 *wh0, *wh1, *wi1;     // packed bf16: [dir][3200][800/800/1600]
  __bf16 *h0, *h1;
  const float *b0f, *b0b, *b1f, *b1b;
  u32* flags;                        // per-WG flag lines, 128 B apart
};

// Flag-array barrier: each WG publishes gen to its own cacheline; wave 0
// ballot-spins on the domain's flags (parallel loads). Busy-poll first.
__device__ __forceinline__ void flag_barrier(u32* flags, unsigned gen,
                                             int base, int count) {
  const int tid = threadIdx.x;
  if (tid < 64) {
    if (tid == 0) ASTORE(flags + (size_t)blockIdx.x * 32, gen);
    int spin = 0;
    for (;;) {
      bool ok = true;
      for (int j = tid; j < count; j += 64)
        ok = ok && (ALOAD(flags + (size_t)(base + j) * 32) >= gen);
      if (__popcll(__ballot(ok)) == 64) break;
      if (++spin > 24) __builtin_amdgcn_s_sleep(1);
    }
  }
  __syncthreads();
}

template <int LAYER>
__device__ __forceinline__ void run_layer(
    const __bf16* __restrict__ Whh,   // (3200,800) bf16, dir-selected
    const __bf16* __restrict__ Wx,    // L0: wx0 dir (3200,64); L1: wi1 dir (3200,1600)
    const float*  __restrict__ bias,
    const __bf16* __restrict__ aux,   // L1 only: h0 [t][b][1600]
    const __bf16* __restrict__ hself, // own-layer h (prev-step source)
    __bf16* __restrict__ hdst,
    const __bf16* __restrict__ zerobuf,
    const __bf16* __restrict__ xpad,
    u32* flags, unsigned& gen, int d, int u0, __bf16* u2) {
  const int tid  = threadIdx.x;
  const int w    = tid >> 6, l = tid & 63;
  const int nidx = l & 15, q = l >> 4;
  const int bL   = l & 31, gl = l >> 5;
  const int dcol = d * 800;
  const int row  = w * 800 + u0 + nidx;          // gate row in [0,3200)
  const float bias_n = bias[row];
  const __bf16* whh_row = Whh + (size_t)row * 800 + q * 8;
  const __bf16* wx_row  = LAYER ? (Wx + (size_t)row * 1600 + q * 8)
                                : (Wx + (size_t)row * 64 + q * 8);
  const int bb = tid >> 3, up = tid & 7;
  float* g_lds = (float*)u2;   // overlays groups 0..15 after MFMAs complete
  __bf16* wlds = u2 + 108 * 256;  // L0 weight store (elems offset 27648)
  float cA = 0.f, cB = 0.f;

  // ---- L0: preload Whh into LDS (once), wx tail into registers ----
  bf16x8 wx_r0, wx_r1;
  if (LAYER == 0) {
#pragma unroll
    for (int sl = 0; sl < 25; ++sl) {
      bf16x8 wv = *(const bf16x8*)(whh_row + sl * 32);
      *(bf16x8*)(wlds + ((size_t)(w * 25 + sl) * 64 + l) * 8) = wv;
    }
    wx_r0 = *(const bf16x8*)(wx_row);
    wx_r1 = *(const bf16x8*)(wx_row + 32);
    __syncthreads();
  }

#pragma unroll 1
  for (int s = 0; s < TT; ++s) {
    const int tt = d ? (TT - 1 - s) : s;
    const __bf16* hprev =
        (s == 0) ? zerobuf
                 : (hself + (size_t)(d ? tt + 1 : tt - 1) * (BT * HROW));

    // L0 x-tail: issue load first
    bf16x8 xv;
    if (LAYER == 0)
      xv = *(const bf16x8*)(xpad + ((size_t)tt * BT + bL) * 64 + (tid >> 5) * 8);

    // h-prev: async cached global->LDS, groups 0..99
    const __bf16* hsrc = hprev + (size_t)bL * HROW + dcol;
#pragma unroll
    for (int i = 0; i < 12; ++i)
      gld_lds16(hsrc + (i * 8 + w * 2 + gl) * 8, u2 + (i * 8 + w * 2) * 256);
    if (w < 2)
      gld_lds16(hsrc + (96 + w * 2 + gl) * 8, u2 + (96 + w * 2) * 256);

    if (LAYER == 0) {
      // x-tail -> groups 100..107
      *(bf16x8*)(u2 + (size_t)(100 + (tid >> 5)) * 256 + bL * 8) = xv;
    } else {
      // aux = h0[t] (stable in phase 2): async cached -> groups 100..299
#pragma unroll
      for (int p = 1; p <= 2; ++p) {
        const __bf16* asrc = aux + ((size_t)tt * BT + bL) * HROW + (p - 1) * 800;
#pragma unroll
        for (int i = 0; i < 12; ++i)
          gld_lds16(asrc + (i * 8 + w * 2 + gl) * 8,
                    u2 + (size_t)(100 * p + i * 8 + w * 2) * 256);
        if (w < 2)
          gld_lds16(asrc + (96 + w * 2 + gl) * 8,
                    u2 + (size_t)(100 * p + 96 + w * 2) * 256);
      }
    }

    asm volatile("s_waitcnt vmcnt(0)" ::: "memory");
    __syncthreads();

    // ---- MFMA: u2 layout [group][b][8]; lane-contiguous ds_read_b128 ----
    f32x4 acc0 = {0.f, 0.f, 0.f, 0.f}, acc1 = {0.f, 0.f, 0.f, 0.f};
    if (LAYER == 0) {
#pragma unroll
      for (int sl = 0; sl < 27; ++sl) {
        bf16x8 bfr;
        if (sl < 25)
          bfr = *(const bf16x8*)(wlds + ((size_t)(w * 25 + sl) * 64 + l) * 8);
        else
          bfr = (sl == 25) ? wx_r0 : wx_r1;
        const __bf16* ab = u2 + (size_t)(sl * 4 + q) * 256 + nidx * 8;
        bf16x8 a0 = *(const bf16x8*)ab;
        bf16x8 a1 = *(const bf16x8*)(ab + 128);
        acc0 = mfma16(a0, bfr, acc0);
        acc1 = mfma16(a1, bfr, acc1);
      }
    } else {
#pragma unroll
      for (int sl = 0; sl < 25; ++sl) {
        bf16x8 bfr = *(const bf16x8*)(whh_row + sl * 32);
        const __bf16* ab = u2 + (size_t)(sl * 4 + q) * 256 + nidx * 8;
        bf16x8 a0 = *(const bf16x8*)ab;
        bf16x8 a1 = *(const bf16x8*)(ab + 128);
        acc0 = mfma16(a0, bfr, acc0);
        acc1 = mfma16(a1, bfr, acc1);
      }
#pragma unroll
      for (int p = 1; p <= 2; ++p) {
#pragma unroll
        for (int sl = 0; sl < 25; ++sl) {
          bf16x8 bfr = *(const bf16x8*)(wx_row + (p - 1) * 800 + sl * 32);
          const __bf16* ab = u2 + (size_t)(100 * p + sl * 4 + q) * 256 + nidx * 8;
          bf16x8 a0 = *(const bf16x8*)ab;
          bf16x8 a1 = *(const bf16x8*)(ab + 128);
          acc0 = mfma16(a0, bfr, acc0);
          acc1 = mfma16(a1, bfr, acc1);
        }
      }
    }
    __syncthreads();

    // ---- gate exchange (C layout: col=nidx=unit, row=q*4+r=batch) ----
#pragma unroll
    for (int r = 0; r < 4; ++r) {
      g_lds[w * 512 + (q * 4 + r) * 16 + nidx]      = acc0[r] + bias_n;
      g_lds[w * 512 + (16 + q * 4 + r) * 16 + nidx] = acc1[r] + bias_n;
    }
    __syncthreads();

    // ---- nonlinearity: thread owns (b=bb, units u0+2up, u0+2up+1) ----
    {
      const int uA = 2 * up, uB = uA + 1;
      float iA = g_lds[0 * 512 + bb * 16 + uA], fA = g_lds[1 * 512 + bb * 16 + uA];
      float gA = g_lds[2 * 512 + bb * 16 + uA], oA = g_lds[3 * 512 + bb * 16 + uA];
      cA = sigf(fA) * cA + sigf(iA) * tanhf(gA);
      float hA = sigf(oA) * tanhf(cA);
      float iB = g_lds[0 * 512 + bb * 16 + uB], fB = g_lds[1 * 512 + bb * 16 + uB];
      float gB = g_lds[2 * 512 + bb * 16 + uB], oB = g_lds[3 * 512 + bb * 16 + uB];
      cB = sigf(fB) * cB + sigf(iB) * tanhf(gB);
      float hB = sigf(oB) * tanhf(cB);
      union { u32 u; __bf16 h2[2]; } pk;
      pk.h2[0] = (__bf16)hA;
      pk.h2[1] = (__bf16)hB;
      ASTORE((u32*)(hdst + ((size_t)tt * BT + bb) * HROW + dcol + u0 + uA), pk.u);
    }

    const bool lastL1 = (LAYER == 1) && (s == TT - 1);
    if (!lastL1) {
      asm volatile("s_waitcnt vmcnt(0)" ::: "memory");  // h stores at coherence pt
      __syncthreads();
      ++gen;
      const bool full = (LAYER == 0) && (s == TT - 1);  // phase transition
      flag_barrier(flags, gen, full ? 0 : d * 50, full ? 100 : 50);
    }
  }
}

__global__ __launch_bounds__(256, 1) void lstm_kernel(LstmArgs A) {
  extern __shared__ __bf16 u2[];   // 157,696 B
  const int wg = blockIdx.x;
  const int d  = wg / 50;
  const int u0 = (wg % 50) * 16;
  unsigned gen = 0;
  run_layer<0>(A.wh0 + (size_t)d * 3200 * 800, A.wx0 + (size_t)d * 3200 * 64,
               d ? A.b0b : A.b0f, nullptr, A.h0, A.h0, A.zero, A.xpad,
               A.flags, gen, d, u0, u2);
  run_layer<1>(A.wh1 + (size_t)d * 3200 * 800, A.wi1 + (size_t)d * 3200 * 1600,
               d ? A.b1b : A.b1f, A.h0, A.h1, A.h1, A.zero, A.xpad,
               A.flags, gen, d, u0, u2);
}

// ---------------- FC + softmax + dihedral -> points ----------------
__global__ __launch_bounds__(256) void fc_kernel(
    const __bf16* __restrict__ h1, const __bf16* __restrict__ xpad,
    const __bf16* __restrict__ wfc, const float* __restrict__ fcb,
    const float* __restrict__ sinA, const float* __restrict__ cosA,
    float* __restrict__ pts) {
  __shared__ float lg[32 * 64];
  const int t = blockIdx.x, tid = threadIdx.x;
  const int wave = tid >> 6, lane = tid & 63, nidx = lane & 15, q = lane >> 4;
  const int a_col = wave * 16 + nidx;
  const __bf16* wrow = wfc + (size_t)a_col * 1664 + q * 8;
  const __bf16* h1row = h1 + (size_t)t * BT * HROW;
  const __bf16* xrow  = xpad + (size_t)t * BT * 64;
  f32x4 acc0 = {0.f, 0.f, 0.f, 0.f}, acc1 = {0.f, 0.f, 0.f, 0.f};
#pragma unroll
  for (int sl = 0; sl < 52; ++sl) {
    const int k = sl * 32 + q * 8;
    bf16x8 a0, a1;
    if (sl < 50) {
      a0 = *(const bf16x8*)(h1row + (size_t)nidx * HROW + k);
      a1 = *(const bf16x8*)(h1row + (size_t)(16 + nidx) * HROW + k);
    } else {
      a0 = *(const bf16x8*)(xrow + nidx * 64 + (k - 1600));
      a1 = *(const bf16x8*)(xrow + (16 + nidx) * 64 + (k - 1600));
    }
    bf16x8 bfr = *(const bf16x8*)(wrow + sl * 32);
    acc0 = mfma16(a0, bfr, acc0);
    acc1 = mfma16(a1, bfr, acc1);
  }
  const float bn = (a_col < 60) ? fcb[a_col] : -1e30f;
#pragma unroll
  for (int r = 0; r < 4; ++r) {
    lg[(q * 4 + r) * 64 + a_col]      = acc0[r] + bn;
    lg[(16 + q * 4 + r) * 64 + a_col] = acc1[r] + bn;
  }
  __syncthreads();

  const int b = tid >> 3, j = tid & 7;
  float v[8];
  float m = -1e30f;
#pragma unroll
  for (int k2 = 0; k2 < 8; ++k2) {
    v[k2] = lg[b * 64 + j + 8 * k2];
    m = fmaxf(m, v[k2]);
  }
  m = fmaxf(m, __shfl_xor(m, 1, 8));
  m = fmaxf(m, __shfl_xor(m, 2, 8));
  m = fmaxf(m, __shfl_xor(m, 4, 8));
  float s = 0.f;
#pragma unroll
  for (int k2 = 0; k2 < 8; ++k2) { v[k2] = __expf(v[k2] - m); s += v[k2]; }
  s += __shfl_xor(s, 1, 8);
  s += __shfl_xor(s, 2, 8);
  s += __shfl_xor(s, 4, 8);
  const float inv = 1.f / s;
  float ps[3] = {0.f, 0.f, 0.f}, pc[3] = {0.f, 0.f, 0.f};
#pragma unroll
  for (int k2 = 0; k2 < 8; ++k2) {
    const int a = j + 8 * k2;
    const float p = v[k2] * inv;
#pragma unroll
    for (int c = 0; c < 3; ++c) {
      ps[c] += p * sinA[a * 3 + c];
      pc[c] += p * cosA[a * 3 + c];
    }
  }
#pragma unroll
  for (int c = 0; c < 3; ++c) {
    ps[c] += __shfl_xor(ps[c], 1, 8);
    ps[c] += __shfl_xor(ps[c], 2, 8);
    ps[c] += __shfl_xor(ps[c], 4, 8);
    pc[c] += __shfl_xor(pc[c], 1, 8);
    pc[c] += __shfl_xor(pc[c], 2, 8);
    pc[c] += __shfl_xor(pc[c], 4, 8);
  }
  if (j == 0) {
    const float BL[3] = {145.801f, 152.326f, 132.868f};
    const float BA[3] = {2.124f, 1.941f, 2.028f};
#pragma unroll
    for (int c = 0; c < 3; ++c) {
      const float ang = 3.14159265358979323846f - BA[c];
      const float rct = BL[c] * cosf(ang), rst = BL[c] * sinf(ang);
      const float dih = atan2f(ps[c], pc[c]);
      float* o = pts + ((size_t)(3 * t + c) * BT + b) * 3;
      o[0] = rct;
      o[1] = cosf(dih) * rst;
      o[2] = sinf(dih) * rst;
    }
  }
}

// ---------------- sequential NeRF extension ----------------
__global__ void nerf_kernel(const float* __restrict__ pts, float* __restrict__ out) {
  const int b = threadIdx.x;
  if (b >= 32) return;
  float ax = -0.70710678f, ay = 1.22474487f, az = 0.f;
  float bx = -1.41421356f, by = 0.f, bz = 0.f;
  float cx = 0.f, cy = 0.f, cz = 0.f;
#pragma unroll 4
  for (int i = 0; i < 3 * TT; ++i) {
    const float* p = pts + ((size_t)i * BT + b) * 3;
    const float p0 = p[0], p1 = p[1], p2 = p[2];
    float ux = cx - bx, uy = cy - by, uz = cz - bz;
    const float ri = rsqrtf(ux * ux + uy * uy + uz * uz + 1e-12f);
    ux *= ri; uy *= ri; uz *= ri;
    const float wx = bx - ax, wy = by - ay, wz = bz - az;
    float nx = wy * uz - wz * uy, ny = wz * ux - wx * uz, nz = wx * uy - wy * ux;
    const float rn = rsqrtf(nx * nx + ny * ny + nz * nz + 1e-12f);
    nx *= rn; ny *= rn; nz *= rn;
    const float mx = ny * uz - nz * uy, my = nz * ux - nx * uz, mz = nx * uy - ny * ux;
    const float ox = cx + p0 * ux + p1 * mx + p2 * nx;
    const float oy = cy + p0 * uy + p1 * my + p2 * ny;
    const float oz = cz + p0 * uz + p1 * mz + p2 * nz;
    out[((size_t)i * BT + b) * 3 + 0] = ox;
    out[((size_t)i * BT + b) * 3 + 1] = oy;
    out[((size_t)i * BT + b) * 3 + 2] = oz;
    ax = bx; ay = by; az = bz;
    bx = cx; by = cy; bz = cz;
    cx = ox; cy = oy; cz = oz;
  }
}

// ---------------- launch ----------------
extern "C" void kernel_launch(void* const* d_in, const int* in_sizes, int n_in,
                              void* d_out, int out_size, void* d_ws, size_t ws_size,
                              hipStream_t stream) {
  (void)in_sizes; (void)n_in; (void)out_size;
  const int*   primary = (const int*)d_in[0];
  const float* evo     = (const float*)d_in[1];
  const float* emb     = (const float*)d_in[3];
  const float* Wih0f   = (const float*)d_in[4];
  const float* Whh0f   = (const float*)d_in[5];
  const float* b0f     = (const float*)d_in[6];
  const float* Wih0b   = (const float*)d_in[7];
  const float* Whh0b   = (const float*)d_in[8];
  const float* b0b     = (const float*)d_in[9];
  const float* Wih1f   = (const float*)d_in[10];
  const float* Whh1f   = (const float*)d_in[11];
  const float* b1f     = (const float*)d_in[12];
  const float* Wih1b   = (const float*)d_in[13];
  const float* Whh1b   = (const float*)d_in[14];
  const float* b1b     = (const float*)d_in[15];
  const float* fcW     = (const float*)d_in[16];
  const float* fcb     = (const float*)d_in[17];
  const float* alpha   = (const float*)d_in[18];

  char* ws = (char*)d_ws;
  size_t off = 0;
  auto take = [&](size_t n) -> void* {
    void* p = ws + off;
    off += (n + 511) & ~(size_t)511;
    return p;
  };
  __bf16* xpad = (__bf16*)take((size_t)TT * BT * 64 * 2);      // 2.87 MB
  __bf16* zb   = (__bf16*)take((size_t)BT * HROW * 2);         // 102 KB
  __bf16* wx0  = (__bf16*)take((size_t)2 * 3200 * 64 * 2);     // 819 KB
  __bf16* wfc  = (__bf16*)take((size_t)64 * 1664 * 2);         // 213 KB
  float*  sinA = (float*)take(192 * 4);
  float*  cosA = (float*)take(192 * 4);
  float*  pts  = (float*)take((size_t)3 * TT * BT * 3 * 4);    // 806 KB
  u32*    flags= (u32*)take(3200 * 4);                          // 12.8 KB
  __bf16* wh0  = (__bf16*)take((size_t)2 * 3200 * 800 * 2);    // 10.24 MB
  __bf16* wh1  = (__bf16*)take((size_t)2 * 3200 * 800 * 2);    // 10.24 MB
  __bf16* wi1  = (__bf16*)take((size_t)2 * 3200 * 1600 * 2);   // 20.48 MB
  __bf16* h0   = (__bf16*)take((size_t)TT * BT * HROW * 2);    // 71.68 MB
  __bf16* h1   = (__bf16*)take((size_t)TT * BT * HROW * 2);    // 71.68 MB
  if (off > ws_size) return;  // failure signature: absmax == max|ref| == 233472

  static int lds_cfg = 0;
  if (!lds_cfg) {   // idempotent attribute set (same value every call)
    hipFuncSetAttribute((const void*)lstm_kernel,
                        hipFuncAttributeMaxDynamicSharedMemorySize, LDS_BYTES);
    lds_cfg = 1;
  }

  const int NW = 3200 * 800;
  const int NI = 3200 * 1600;
  cvt_f32_bf16_kernel<<<2048, 256, 0, stream>>>(Whh0f, wh0, NW);
  cvt_f32_bf16_kernel<<<2048, 256, 0, stream>>>(Whh0b, wh0 + NW, NW);
  cvt_f32_bf16_kernel<<<2048, 256, 0, stream>>>(Whh1f, wh1, NW);
  cvt_f32_bf16_kernel<<<2048, 256, 0, stream>>>(Whh1b, wh1 + NW, NW);
  cvt_f32_bf16_kernel<<<2048, 256, 0, stream>>>(Wih1f, wi1, NI);
  cvt_f32_bf16_kernel<<<2048, 256, 0, stream>>>(Wih1b, wi1 + NI, NI);
  pack_wx0_kernel<<<1600, 256, 0, stream>>>(Wih0f, Wih0b, wx0);
  pack_fc_kernel<<<(64 * 1664 + 255) / 256, 256, 0, stream>>>(fcW, wfc);
  xpad_kernel<<<(TT * BT * 64) / 256, 256, 0, stream>>>(primary, evo, emb, xpad);
  small_init_kernel<<<202, 256, 0, stream>>>(zb, flags, sinA, cosA, alpha);

  LstmArgs a;
  a.xpad = xpad; a.wx0 = wx0; a.zero = zb;
  a.wh0 = wh0; a.wh1 = wh1; a.wi1 = wi1;
  a.h0 = h0; a.h1 = h1;
  a.b0f = b0f; a.b0b = b0b; a.b1f = b1f; a.b1b = b1b;
  a.flags = flags;
  lstm_kernel<<<NWG, 256, LDS_BYTES, stream>>>(a);

  fc_kernel<<<TT, 256, 0, stream>>>(h1, xpad, wfc, fcb, sinA, cosA, pts);
  nerf_kernel<<<1, 64, 0, stream>>>(pts, (float*)d_out);
}

// Round 7
// 13781.929 us; speedup vs baseline: 1.6306x; 1.5320x over previous
//
#include <hip/hip_runtime.h>
#include <hip/hip_bf16.h>
#include <math.h>

// ---------------------------------------------------------------------------
// RGN model: T=700 B=32 H=800 EMB=32 EVO=21 A=60
// f32 in / f32 out; internal bf16 MFMA.
// Persistent biLSTM. Per step: plain L2-allocating h-prev loads overlap with
// the aux MFMA chain (aux operand pre-staged into LDS via async DMA during
// the PREVIOUS step's barrier spin). L0 weights LDS-resident. h rows padded
// (HROW=1664) so fwd/bwd halves never share a cache line.
// ---------------------------------------------------------------------------

typedef unsigned int u32;
typedef __bf16 bf16x8 __attribute__((ext_vector_type(8)));
typedef float  f32x4  __attribute__((ext_vector_type(4)));

#define TT 700
#define BT 32
#define HROW 1664          // 800 fwd | 32 pad | 800 bwd | 32 pad (line-aligned)
#define NWG 100
#define LDS_BYTES 157696   // 108*512 staging + 102400 L0 weights (L1: 300*512)

__device__ __forceinline__ f32x4 mfma16(bf16x8 a, bf16x8 b, f32x4 c) {
  return __builtin_amdgcn_mfma_f32_16x16x32_bf16(a, b, c, 0, 0, 0);
}
__device__ __forceinline__ float sigf(float x) { return 1.f / (1.f + __expf(-x)); }

#define ALOAD(p)    __hip_atomic_load((p), __ATOMIC_RELAXED, __HIP_MEMORY_SCOPE_AGENT)
#define ASTORE(p,v) __hip_atomic_store((p), (v), __ATOMIC_RELAXED, __HIP_MEMORY_SCOPE_AGENT)

__device__ __forceinline__ void gld_lds16(const __bf16* g, __bf16* l) {
  __builtin_amdgcn_global_load_lds(
      (const __attribute__((address_space(1))) unsigned int*)g,
      (__attribute__((address_space(3))) unsigned int*)l, 16, 0, 0);
}

// ---------------- pack / init kernels ----------------
__global__ void cvt_f32_bf16_kernel(const float* __restrict__ src,
                                    __bf16* __restrict__ dst, int n) {
  for (int i = blockIdx.x * 256 + threadIdx.x; i < n; i += gridDim.x * 256)
    dst[i] = (__bf16)src[i];
}

__global__ void pack_wx0_kernel(const float* Wih0f, const float* Wih0b, __bf16* wx0) {
  int idx = blockIdx.x * 256 + threadIdx.x;      // 2*3200*64 exact
  if (idx >= 2 * 3200 * 64) return;
  int d = idx / (3200 * 64);
  int r = (idx / 64) % 3200;
  int k = idx % 64;
  const float* W = d ? Wih0b : Wih0f;
  wx0[idx] = (k < 53) ? (__bf16)W[(size_t)r * 53 + k] : (__bf16)0.f;
}

__global__ void pack_fc_kernel(const float* fcW, __bf16* wfc) {
  int idx = blockIdx.x * 256 + threadIdx.x;
  if (idx >= 64 * 1664) return;
  int a = idx / 1664, k = idx % 1664;
  __bf16 v = (__bf16)0.f;
  if (a < 60 && k < 1653) v = (__bf16)fcW[(size_t)a * 1653 + k];
  wfc[idx] = v;
}

__global__ void xpad_kernel(const int* primary, const float* evo,
                            const float* emb, __bf16* xpad) {
  int idx = blockIdx.x * 256 + threadIdx.x;   // 700*32*64 exact
  int t = idx >> 11;
  int b = (idx >> 6) & 31;
  int k = idx & 63;
  __bf16 v = (__bf16)0.f;
  if (k < 32)      v = (__bf16)emb[primary[t * 32 + b] * 32 + k];
  else if (k < 53) v = (__bf16)evo[((size_t)t * 32 + b) * 21 + (k - 32)];
  xpad[idx] = v;
}

__global__ void small_init_kernel(__bf16* zerobuf, u32* flags,
                                  float* sinA, float* cosA, const float* alpha) {
  int idx = blockIdx.x * 256 + threadIdx.x;
  if (idx < 32 * HROW) zerobuf[idx] = (__bf16)0.f;
  if (idx < 3200) flags[idx] = 0u;
  int j = idx - 32 * HROW;
  if (j >= 0 && j < 192) {
    if (j < 180) {
      float v = alpha[j];
      sinA[j] = sinf(v);
      cosA[j] = cosf(v);
    } else { sinA[j] = 0.f; cosA[j] = 0.f; }
  }
}

// ---------------- persistent biLSTM ----------------
struct LstmArgs {
  const __bf16 *xpad, *wx0, *zero;
  const __bf16 *wh0, *wh1, *wi1;     // packed bf16: [dir][3200][800/800/1600]
  __bf16 *h0, *h1;
  const float *b0f, *b0b, *b1f, *b1b;
  u32* flags;                        // per-WG flag lines, 128 B apart
};

// Async-DMA the aux operand (h0[t], both dirs, 800 cols each at 0 / 832)
// into LDS groups 100..299. Issued during the barrier spin window.
__device__ __forceinline__ void stage_aux(const __bf16* aux, int t,
                                          int w, int gl, int bL, __bf16* u2) {
#pragma unroll
  for (int p = 1; p <= 2; ++p) {
    const __bf16* asrc = aux + ((size_t)t * BT + bL) * HROW + (p - 1) * 832;
#pragma unroll
    for (int i = 0; i < 12; ++i)
      gld_lds16(asrc + (i * 8 + w * 2 + gl) * 8,
                u2 + (size_t)(100 * p + i * 8 + w * 2) * 256);
    if (w < 2)
      gld_lds16(asrc + (96 + w * 2 + gl) * 8,
                u2 + (size_t)(100 * p + 96 + w * 2) * 256);
  }
}

template <int LAYER>
__device__ __forceinline__ void run_layer(
    const __bf16* __restrict__ Whh,   // (3200,800) bf16, dir-selected
    const __bf16* __restrict__ Wx,    // L0: wx0 dir (3200,64); L1: wi1 dir (3200,1600)
    const float*  __restrict__ bias,
    const __bf16* __restrict__ aux,   // L1 only: h0 [t][b][HROW]
    const __bf16* __restrict__ hself,
    __bf16* __restrict__ hdst,
    const __bf16* __restrict__ zerobuf,
    const __bf16* __restrict__ xpad,
    u32* flags, unsigned& gen, int d, int u0, __bf16* u2) {
  const int tid  = threadIdx.x;
  const int w    = tid >> 6, l = tid & 63;
  const int nidx = l & 15, q = l >> 4;
  const int bL   = l & 31, gl = l >> 5;
  const int dcol = d * 832;
  const int row  = w * 800 + u0 + nidx;          // gate row in [0,3200)
  const float bias_n = bias[row];
  const __bf16* whh_row = Whh + (size_t)row * 800 + q * 8;
  const __bf16* wx_row  = LAYER ? (Wx + (size_t)row * 1600 + q * 8)
                                : (Wx + (size_t)row * 64 + q * 8);
  const int bb = tid >> 3, up = tid & 7;
  float* g_lds = (float*)u2;          // overlays groups 0..15
  __bf16* wlds = u2 + 108 * 256;      // L0 weight store
  float cA = 0.f, cB = 0.f;

  // ---- L0: preload Whh into LDS once; wx tail into registers ----
  bf16x8 wx_r0, wx_r1;
  if (LAYER == 0) {
#pragma unroll
    for (int sl = 0; sl < 25; ++sl) {
      bf16x8 wv = *(const bf16x8*)(whh_row + sl * 32);
      *(bf16x8*)(wlds + ((size_t)(w * 25 + sl) * 64 + l) * 8) = wv;
    }
    wx_r0 = *(const bf16x8*)(wx_row);
    wx_r1 = *(const bf16x8*)(wx_row + 32);
    __syncthreads();
  } else {
    // L1 prologue: stage aux for the first step (drained at step 0)
    stage_aux(aux, d ? (TT - 1) : 0, w, gl, bL, u2);
  }

#pragma unroll 1
  for (int s = 0; s < TT; ++s) {
    const int tt = d ? (TT - 1 - s) : s;
    const __bf16* hprev =
        (s == 0) ? zerobuf
                 : (hself + (size_t)(d ? tt + 1 : tt - 1) * (BT * HROW));

    // ---- issue h-prev plain loads (L2-allocating, cross-WG shared) ----
    bf16x8 hreg[13];
    const __bf16* hsrc = hprev + (size_t)bL * HROW + dcol;
#pragma unroll
    for (int i = 0; i < 12; ++i)
      hreg[i] = *(const bf16x8*)(hsrc + (i * 8 + w * 2 + gl) * 8);
    if (w < 2) hreg[12] = *(const bf16x8*)(hsrc + (96 + w * 2 + gl) * 8);

    bf16x8 xv;
    if (LAYER == 0)
      xv = *(const bf16x8*)(xpad + ((size_t)tt * BT + bL) * 64 + (tid >> 5) * 8);

    f32x4 acc0 = {0.f, 0.f, 0.f, 0.f}, acc1 = {0.f, 0.f, 0.f, 0.f};

    if (LAYER == 1) {
      // drain this wave's aux DMAs (h-prev loads may stay in flight), sync X
      asm volatile("s_waitcnt vmcnt(12)" ::: "memory");
      __syncthreads();
      // ---- aux chain (2/3 of work) overlaps the h-prev load latency ----
#pragma unroll
      for (int p = 1; p <= 2; ++p) {
#pragma unroll
        for (int sl = 0; sl < 25; ++sl) {
          bf16x8 bfr = *(const bf16x8*)(wx_row + (p - 1) * 800 + sl * 32);
          const __bf16* ab = u2 + (size_t)(100 * p + sl * 4 + q) * 256 + nidx * 8;
          bf16x8 a0 = *(const bf16x8*)ab;
          bf16x8 a1 = *(const bf16x8*)(ab + 128);
          acc0 = mfma16(a0, bfr, acc0);
          acc1 = mfma16(a1, bfr, acc1);
        }
      }
    }

    // ---- stage h-prev (and L0 x) into LDS ----
#pragma unroll
    for (int i = 0; i < 12; ++i)
      *(bf16x8*)(u2 + (size_t)(i * 8 + w * 2 + gl) * 256 + bL * 8) = hreg[i];
    if (w < 2)
      *(bf16x8*)(u2 + (size_t)(96 + w * 2 + gl) * 256 + bL * 8) = hreg[12];
    if (LAYER == 0)
      *(bf16x8*)(u2 + (size_t)(100 + (tid >> 5)) * 256 + bL * 8) = xv;
    __syncthreads();

    // ---- recurrent (Whh) chain ----
    if (LAYER == 0) {
#pragma unroll
      for (int sl = 0; sl < 27; ++sl) {
        bf16x8 bfr;
        if (sl < 25)
          bfr = *(const bf16x8*)(wlds + ((size_t)(w * 25 + sl) * 64 + l) * 8);
        else
          bfr = (sl == 25) ? wx_r0 : wx_r1;
        const __bf16* ab = u2 + (size_t)(sl * 4 + q) * 256 + nidx * 8;
        bf16x8 a0 = *(const bf16x8*)ab;
        bf16x8 a1 = *(const bf16x8*)(ab + 128);
        acc0 = mfma16(a0, bfr, acc0);
        acc1 = mfma16(a1, bfr, acc1);
      }
    } else {
#pragma unroll
      for (int sl = 0; sl < 25; ++sl) {
        bf16x8 bfr = *(const bf16x8*)(whh_row + sl * 32);
        const __bf16* ab = u2 + (size_t)(sl * 4 + q) * 256 + nidx * 8;
        bf16x8 a0 = *(const bf16x8*)ab;
        bf16x8 a1 = *(const bf16x8*)(ab + 128);
        acc0 = mfma16(a0, bfr, acc0);
        acc1 = mfma16(a1, bfr, acc1);
      }
    }
    __syncthreads();

    // ---- gate exchange (C layout: col=nidx=unit, row=q*4+r=batch) ----
#pragma unroll
    for (int r = 0; r < 4; ++r) {
      g_lds[w * 512 + (q * 4 + r) * 16 + nidx]      = acc0[r] + bias_n;
      g_lds[w * 512 + (16 + q * 4 + r) * 16 + nidx] = acc1[r] + bias_n;
    }
    __syncthreads();

    // ---- nonlinearity: thread owns (b=bb, units u0+2up, u0+2up+1) ----
    {
      const int uA = 2 * up, uB = uA + 1;
      float iA = g_lds[0 * 512 + bb * 16 + uA], fA = g_lds[1 * 512 + bb * 16 + uA];
      float gA = g_lds[2 * 512 + bb * 16 + uA], oA = g_lds[3 * 512 + bb * 16 + uA];
      cA = sigf(fA) * cA + sigf(iA) * tanhf(gA);
      float hA = sigf(oA) * tanhf(cA);
      float iB = g_lds[0 * 512 + bb * 16 + uB], fB = g_lds[1 * 512 + bb * 16 + uB];
      float gB = g_lds[2 * 512 + bb * 16 + uB], oB = g_lds[3 * 512 + bb * 16 + uB];
      cB = sigf(fB) * cB + sigf(iB) * tanhf(gB);
      float hB = sigf(oB) * tanhf(cB);
      union { u32 u; __bf16 h2[2]; } pk;
      pk.h2[0] = (__bf16)hA;
      pk.h2[1] = (__bf16)hB;
      ASTORE((u32*)(hdst + ((size_t)tt * BT + bb) * HROW + dcol + u0 + uA), pk.u);
    }

    const bool lastL1 = (LAYER == 1) && (s == TT - 1);
    if (!lastL1) {
      asm volatile("s_waitcnt vmcnt(0)" ::: "memory");  // h stores visible
      __syncthreads();
      ++gen;
      if (tid == 0) ASTORE(flags + (size_t)blockIdx.x * 32, gen);
      if (LAYER == 1)   // prefetch aux for next step during the spin window
        stage_aux(aux, d ? (TT - 2 - s) : (s + 1), w, gl, bL, u2);
      const bool full = (LAYER == 0) && (s == TT - 1);  // phase transition
      const int base = full ? 0 : d * 50;
      const int count = full ? NWG : 50;
      if (tid < 64) {
        int spin = 0;
        for (;;) {
          bool ok = true;
          for (int j = l; j < count; j += 64)
            ok = ok && (ALOAD(flags + (size_t)(base + j) * 32) >= gen);
          if (__popcll(__ballot(ok)) == 64) break;
          if (++spin > 24) __builtin_amdgcn_s_sleep(1);
        }
      }
      __syncthreads();
    }
  }
}

__global__ __launch_bounds__(256, 1) void lstm_kernel(LstmArgs A) {
  extern __shared__ __bf16 u2[];
  const int wg = blockIdx.x;
  const int d  = wg / 50;
  const int u0 = (wg % 50) * 16;
  unsigned gen = 0;
  run_layer<0>(A.wh0 + (size_t)d * 3200 * 800, A.wx0 + (size_t)d * 3200 * 64,
               d ? A.b0b : A.b0f, nullptr, A.h0, A.h0, A.zero, A.xpad,
               A.flags, gen, d, u0, u2);
  run_layer<1>(A.wh1 + (size_t)d * 3200 * 800, A.wi1 + (size_t)d * 3200 * 1600,
               d ? A.b1b : A.b1f, A.h0, A.h1, A.h1, A.zero, A.xpad,
               A.flags, gen, d, u0, u2);
}

// ---------------- FC + softmax + dihedral -> points ----------------
__global__ __launch_bounds__(256) void fc_kernel(
    const __bf16* __restrict__ h1, const __bf16* __restrict__ xpad,
    const __bf16* __restrict__ wfc, const float* __restrict__ fcb,
    const float* __restrict__ sinA, const float* __restrict__ cosA,
    float* __restrict__ pts) {
  __shared__ float lg[32 * 64];
  const int t = blockIdx.x, tid = threadIdx.x;
  const int wave = tid >> 6, lane = tid & 63, nidx = lane & 15, q = lane >> 4;
  const int a_col = wave * 16 + nidx;
  const __bf16* wrow = wfc + (size_t)a_col * 1664 + q * 8;
  const __bf16* h1row = h1 + (size_t)t * BT * HROW;
  const __bf16* xrow  = xpad + (size_t)t * BT * 64;
  f32x4 acc0 = {0.f, 0.f, 0.f, 0.f}, acc1 = {0.f, 0.f, 0.f, 0.f};
#pragma unroll
  for (int sl = 0; sl < 52; ++sl) {
    const int k = sl * 32 + q * 8;
    bf16x8 a0, a1;
    if (sl < 50) {
      const int kp = (sl < 25) ? k : (k + 32);   // physical col (832-offset bwd)
      a0 = *(const bf16x8*)(h1row + (size_t)nidx * HROW + kp);
      a1 = *(const bf16x8*)(h1row + (size_t)(16 + nidx) * HROW + kp);
    } else {
      a0 = *(const bf16x8*)(xrow + nidx * 64 + (k - 1600));
      a1 = *(const bf16x8*)(xrow + (16 + nidx) * 64 + (k - 1600));
    }
    bf16x8 bfr = *(const bf16x8*)(wrow + sl * 32);
    acc0 = mfma16(a0, bfr, acc0);
    acc1 = mfma16(a1, bfr, acc1);
  }
  const float bn = (a_col < 60) ? fcb[a_col] : -1e30f;
#pragma unroll
  for (int r = 0; r < 4; ++r) {
    lg[(q * 4 + r) * 64 + a_col]      = acc0[r] + bn;
    lg[(16 + q * 4 + r) * 64 + a_col] = acc1[r] + bn;
  }
  __syncthreads();

  const int b = tid >> 3, j = tid & 7;
  float v[8];
  float m = -1e30f;
#pragma unroll
  for (int k2 = 0; k2 < 8; ++k2) {
    v[k2] = lg[b * 64 + j + 8 * k2];
    m = fmaxf(m, v[k2]);
  }
  m = fmaxf(m, __shfl_xor(m, 1, 8));
  m = fmaxf(m, __shfl_xor(m, 2, 8));
  m = fmaxf(m, __shfl_xor(m, 4, 8));
  float s = 0.f;
#pragma unroll
  for (int k2 = 0; k2 < 8; ++k2) { v[k2] = __expf(v[k2] - m); s += v[k2]; }
  s += __shfl_xor(s, 1, 8);
  s += __shfl_xor(s, 2, 8);
  s += __shfl_xor(s, 4, 8);
  const float inv = 1.f / s;
  float ps[3] = {0.f, 0.f, 0.f}, pc[3] = {0.f, 0.f, 0.f};
#pragma unroll
  for (int k2 = 0; k2 < 8; ++k2) {
    const int a = j + 8 * k2;
    const float p = v[k2] * inv;
#pragma unroll
    for (int c = 0; c < 3; ++c) {
      ps[c] += p * sinA[a * 3 + c];
      pc[c] += p * cosA[a * 3 + c];
    }
  }
#pragma unroll
  for (int c = 0; c < 3; ++c) {
    ps[c] += __shfl_xor(ps[c], 1, 8);
    ps[c] += __shfl_xor(ps[c], 2, 8);
    ps[c] += __shfl_xor(ps[c], 4, 8);
    pc[c] += __shfl_xor(pc[c], 1, 8);
    pc[c] += __shfl_xor(pc[c], 2, 8);
    pc[c] += __shfl_xor(pc[c], 4, 8);
  }
  if (j == 0) {
    const float BL[3] = {145.801f, 152.326f, 132.868f};
    const float BA[3] = {2.124f, 1.941f, 2.028f};
#pragma unroll
    for (int c = 0; c < 3; ++c) {
      const float ang = 3.14159265358979323846f - BA[c];
      const float rct = BL[c] * cosf(ang), rst = BL[c] * sinf(ang);
      const float dih = atan2f(ps[c], pc[c]);
      float* o = pts + ((size_t)(3 * t + c) * BT + b) * 3;
      o[0] = rct;
      o[1] = cosf(dih) * rst;
      o[2] = sinf(dih) * rst;
    }
  }
}

// ---------------- sequential NeRF extension ----------------
__global__ void nerf_kernel(const float* __restrict__ pts, float* __restrict__ out) {
  const int b = threadIdx.x;
  if (b >= 32) return;
  float ax = -0.70710678f, ay = 1.22474487f, az = 0.f;
  float bx = -1.41421356f, by = 0.f, bz = 0.f;
  float cx = 0.f, cy = 0.f, cz = 0.f;
#pragma unroll 4
  for (int i = 0; i < 3 * TT; ++i) {
    const float* p = pts + ((size_t)i * BT + b) * 3;
    const float p0 = p[0], p1 = p[1], p2 = p[2];
    float ux = cx - bx, uy = cy - by, uz = cz - bz;
    const float ri = rsqrtf(ux * ux + uy * uy + uz * uz + 1e-12f);
    ux *= ri; uy *= ri; uz *= ri;
    const float wx = bx - ax, wy = by - ay, wz = bz - az;
    float nx = wy * uz - wz * uy, ny = wz * ux - wx * uz, nz = wx * uy - wy * ux;
    const float rn = rsqrtf(nx * nx + ny * ny + nz * nz + 1e-12f);
    nx *= rn; ny *= rn; nz *= rn;
    const float mx = ny * uz - nz * uy, my = nz * ux - nx * uz, mz = nx * uy - ny * ux;
    const float ox = cx + p0 * ux + p1 * mx + p2 * nx;
    const float oy = cy + p0 * uy + p1 * my + p2 * ny;
    const float oz = cz + p0 * uz + p1 * mz + p2 * nz;
    out[((size_t)i * BT + b) * 3 + 0] = ox;
    out[((size_t)i * BT + b) * 3 + 1] = oy;
    out[((size_t)i * BT + b) * 3 + 2] = oz;
    ax = bx; ay = by; az = bz;
    bx = cx; by = cy; bz = cz;
    cx = ox; cy = oy; cz = oz;
  }
}

// ---------------- launch ----------------
extern "C" void kernel_launch(void* const* d_in, const int* in_sizes, int n_in,
                              void* d_out, int out_size, void* d_ws, size_t ws_size,
                              hipStream_t stream) {
  (void)in_sizes; (void)n_in; (void)out_size;
  const int*   primary = (const int*)d_in[0];
  const float* evo     = (const float*)d_in[1];
  const float* emb     = (const float*)d_in[3];
  const float* Wih0f   = (const float*)d_in[4];
  const float* Whh0f   = (const float*)d_in[5];
  const float* b0f     = (const float*)d_in[6];
  const float* Wih0b   = (const float*)d_in[7];
  const float* Whh0b   = (const float*)d_in[8];
  const float* b0b     = (const float*)d_in[9];
  const float* Wih1f   = (const float*)d_in[10];
  const float* Whh1f   = (const float*)d_in[11];
  const float* b1f     = (const float*)d_in[12];
  const float* Wih1b   = (const float*)d_in[13];
  const float* Whh1b   = (const float*)d_in[14];
  const float* b1b     = (const float*)d_in[15];
  const float* fcW     = (const float*)d_in[16];
  const float* fcb     = (const float*)d_in[17];
  const float* alpha   = (const float*)d_in[18];

  char* ws = (char*)d_ws;
  size_t off = 0;
  auto take = [&](size_t n) -> void* {
    void* p = ws + off;
    off += (n + 511) & ~(size_t)511;
    return p;
  };
  __bf16* xpad = (__bf16*)take((size_t)TT * BT * 64 * 2);      // 2.87 MB
  __bf16* zb   = (__bf16*)take((size_t)BT * HROW * 2);         // 106 KB
  __bf16* wx0  = (__bf16*)take((size_t)2 * 3200 * 64 * 2);     // 819 KB
  __bf16* wfc  = (__bf16*)take((size_t)64 * 1664 * 2);         // 213 KB
  float*  sinA = (float*)take(192 * 4);
  float*  cosA = (float*)take(192 * 4);
  float*  pts  = (float*)take((size_t)3 * TT * BT * 3 * 4);    // 806 KB
  u32*    flags= (u32*)take(3200 * 4);                          // 12.8 KB
  __bf16* wh0  = (__bf16*)take((size_t)2 * 3200 * 800 * 2);    // 10.24 MB
  __bf16* wh1  = (__bf16*)take((size_t)2 * 3200 * 800 * 2);    // 10.24 MB
  __bf16* wi1  = (__bf16*)take((size_t)2 * 3200 * 1600 * 2);   // 20.48 MB
  __bf16* h0   = (__bf16*)take((size_t)TT * BT * HROW * 2);    // 74.5 MB
  __bf16* h1   = (__bf16*)take((size_t)TT * BT * HROW * 2);    // 74.5 MB
  if (off > ws_size) return;  // failure signature: absmax == max|ref| == 233472

  static int lds_cfg = 0;
  if (!lds_cfg) {
    hipFuncSetAttribute((const void*)lstm_kernel,
                        hipFuncAttributeMaxDynamicSharedMemorySize, LDS_BYTES);
    lds_cfg = 1;
  }

  const int NW = 3200 * 800;
  const int NI = 3200 * 1600;
  cvt_f32_bf16_kernel<<<2048, 256, 0, stream>>>(Whh0f, wh0, NW);
  cvt_f32_bf16_kernel<<<2048, 256, 0, stream>>>(Whh0b, wh0 + NW, NW);
  cvt_f32_bf16_kernel<<<2048, 256, 0, stream>>>(Whh1f, wh1, NW);
  cvt_f32_bf16_kernel<<<2048, 256, 0, stream>>>(Whh1b, wh1 + NW, NW);
  cvt_f32_bf16_kernel<<<2048, 256, 0, stream>>>(Wih1f, wi1, NI);
  cvt_f32_bf16_kernel<<<2048, 256, 0, stream>>>(Wih1b, wi1 + NI, NI);
  pack_wx0_kernel<<<1600, 256, 0, stream>>>(Wih0f, Wih0b, wx0);
  pack_fc_kernel<<<(64 * 1664 + 255) / 256, 256, 0, stream>>>(fcW, wfc);
  xpad_kernel<<<(TT * BT * 64) / 256, 256, 0, stream>>>(primary, evo, emb, xpad);
  small_init_kernel<<<209, 256, 0, stream>>>(zb, flags, sinA, cosA, alpha);

  LstmArgs a;
  a.xpad = xpad; a.wx0 = wx0; a.zero = zb;
  a.wh0 = wh0; a.wh1 = wh1; a.wi1 = wi1;
  a.h0 = h0; a.h1 = h1;
  a.b0f = b0f; a.b0b = b0b; a.b1f = b1f; a.b1b = b1b;
  a.flags = flags;
  lstm_kernel<<<NWG, 256, LDS_BYTES, stream>>>(a);

  fc_kernel<<<TT, 256, 0, stream>>>(h1, xpad, wfc, fcb, sinA, cosA, pts);
  nerf_kernel<<<1, 64, 0, stream>>>(pts, (float*)d_out);
}

// Round 8
// 13178.438 us; speedup vs baseline: 1.7053x; 1.0458x over previous
//
#include <hip/hip_runtime.h>
#include <hip/hip_bf16.h>
#include <math.h>

// ---------------------------------------------------------------------------
// RGN model: T=700 B=32 H=800 EMB=32 EVO=21 A=60
// f32 in / f32 out; internal bf16 MFMA.
// L0: persistent recurrence, Whh0 LDS-resident, x-part in-step (K=64).
// L1: xg1 = Wih1*h0 + b1 precomputed by chunked dense GEMM (all CUs),
//     interleaved with persistent recurrence launches (Whh1 LDS-resident,
//     c-state spilled across chunks). Flag barrier, 50-WG fwd/bwd domains.
// ---------------------------------------------------------------------------

typedef unsigned int u32;
typedef __bf16 bf16x8 __attribute__((ext_vector_type(8)));
typedef __bf16 bf16x4 __attribute__((ext_vector_type(4)));
typedef float  f32x4  __attribute__((ext_vector_type(4)));

#define TT 700
#define BT 32
#define HROW 1664          // 800 fwd | 32 pad | 800 bwd | 32 pad
#define NWG 100
#define CH 50              // L1 chunk length (14 chunks)
#define LDS_L0 (108 * 512 + 102400)   // 157,696 B
#define LDS_L1 (100 * 512 + 102400)   // 153,600 B
#define LDS_GM (200 * 512)            // 102,400 B

__device__ __forceinline__ f32x4 mfma16(bf16x8 a, bf16x8 b, f32x4 c) {
  return __builtin_amdgcn_mfma_f32_16x16x32_bf16(a, b, c, 0, 0, 0);
}
__device__ __forceinline__ float sigf(float x) { return 1.f / (1.f + __expf(-x)); }

#define ALOAD(p)    __hip_atomic_load((p), __ATOMIC_RELAXED, __HIP_MEMORY_SCOPE_AGENT)
#define ASTORE(p,v) __hip_atomic_store((p), (v), __ATOMIC_RELAXED, __HIP_MEMORY_SCOPE_AGENT)

__device__ __forceinline__ bf16x8 cvt8(f32x4 a, f32x4 b) {
  bf16x8 r;
  r[0] = (__bf16)a[0]; r[1] = (__bf16)a[1]; r[2] = (__bf16)a[2]; r[3] = (__bf16)a[3];
  r[4] = (__bf16)b[0]; r[5] = (__bf16)b[1]; r[6] = (__bf16)b[2]; r[7] = (__bf16)b[3];
  return r;
}

// ---------------- pack / init kernels ----------------
__global__ void pack_wx0_kernel(const float* Wih0f, const float* Wih0b, __bf16* wx0) {
  int idx = blockIdx.x * 256 + threadIdx.x;      // 2*3200*64 exact
  if (idx >= 2 * 3200 * 64) return;
  int d = idx / (3200 * 64);
  int r = (idx / 64) % 3200;
  int k = idx % 64;
  const float* W = d ? Wih0b : Wih0f;
  wx0[idx] = (k < 53) ? (__bf16)W[(size_t)r * 53 + k] : (__bf16)0.f;
}

__global__ void pack_fc_kernel(const float* fcW, __bf16* wfc) {
  int idx = blockIdx.x * 256 + threadIdx.x;
  if (idx >= 64 * 1664) return;
  int a = idx / 1664, k = idx % 1664;
  __bf16 v = (__bf16)0.f;
  if (a < 60 && k < 1653) v = (__bf16)fcW[(size_t)a * 1653 + k];
  wfc[idx] = v;
}

__global__ void xpad_kernel(const int* primary, const float* evo,
                            const float* emb, __bf16* xpad) {
  int idx = blockIdx.x * 256 + threadIdx.x;   // 700*32*64 exact
  int t = idx >> 11;
  int b = (idx >> 6) & 31;
  int k = idx & 63;
  __bf16 v = (__bf16)0.f;
  if (k < 32)      v = (__bf16)emb[primary[t * 32 + b] * 32 + k];
  else if (k < 53) v = (__bf16)evo[((size_t)t * 32 + b) * 21 + (k - 32)];
  xpad[idx] = v;
}

__global__ void small_init_kernel(__bf16* zerobuf, u32* flags,
                                  float* sinA, float* cosA, const float* alpha) {
  int idx = blockIdx.x * 256 + threadIdx.x;
  if (idx < 32 * HROW) zerobuf[idx] = (__bf16)0.f;
  if (idx < 6400) flags[idx] = 0u;   // flags0 (3200) + flags1 (3200)
  int j = idx - 32 * HROW;
  if (j >= 0 && j < 192) {
    if (j < 180) {
      float v = alpha[j];
      sinA[j] = sinf(v);
      cosA[j] = cosf(v);
    } else { sinA[j] = 0.f; cosA[j] = 0.f; }
  }
}

// ---------------- barrier ----------------
__device__ __forceinline__ void rec_barrier(u32* flags, unsigned gen,
                                            int base, int count) {
  asm volatile("s_waitcnt vmcnt(0)" ::: "memory");  // h stores at coherence pt
  __syncthreads();
  const int tid = threadIdx.x;
  if (tid == 0) ASTORE(flags + (size_t)blockIdx.x * 32, gen);
  if (tid < 64) {
    int spin = 0;
    for (;;) {
      bool ok = true;
      for (int j = tid; j < count; j += 64)
        ok = ok && (ALOAD(flags + (size_t)(base + j) * 32) >= gen);
      if (__popcll(__ballot(ok)) == 64) break;
      if (++spin > 24) __builtin_amdgcn_s_sleep(1);
    }
  }
  __syncthreads();
}

// ---------------- L0 persistent recurrence ----------------
struct L0Args {
  const __bf16 *xpad, *wx0, *zero;
  const float *Whh0f, *Whh0b, *b0f, *b0b;
  __bf16* h0;
  u32* flags;
};

__global__ __launch_bounds__(256, 1) void lstm_l0(L0Args A) {
  extern __shared__ __bf16 u2[];
  const int wg = blockIdx.x, d = wg / 50, u0 = (wg % 50) * 16;
  const int tid = threadIdx.x, w = tid >> 6, l = tid & 63;
  const int nidx = l & 15, q = l >> 4, bL = l & 31, gl = l >> 5;
  const int dcol = d * 832;
  const int row = w * 800 + u0 + nidx;
  const float bias_n = (d ? A.b0b : A.b0f)[row];
  const float* wrf = (d ? A.Whh0b : A.Whh0f) + (size_t)row * 800 + q * 8;
  __bf16* wlds = u2 + 108 * 256;
  float* g_lds = (float*)u2;
  const int bb = tid >> 3, up = tid & 7;

  // preload Whh0 (f32 -> bf16) into LDS
#pragma unroll
  for (int sl = 0; sl < 25; ++sl) {
    f32x4 wa = *(const f32x4*)(wrf + sl * 32);
    f32x4 wb = *(const f32x4*)(wrf + sl * 32 + 4);
    *(bf16x8*)(wlds + ((size_t)(w * 25 + sl) * 64 + l) * 8) = cvt8(wa, wb);
  }
  const __bf16* wx_row = A.wx0 + (size_t)d * 3200 * 64 + (size_t)row * 64 + q * 8;
  bf16x8 wx_r0 = *(const bf16x8*)wx_row;
  bf16x8 wx_r1 = *(const bf16x8*)(wx_row + 32);
  __syncthreads();

  float cA = 0.f, cB = 0.f;
#pragma unroll 1
  for (int s = 0; s < TT; ++s) {
    const int tt = d ? (TT - 1 - s) : s;
    const __bf16* hprev =
        (s == 0) ? A.zero : (A.h0 + (size_t)(d ? tt + 1 : tt - 1) * (BT * HROW));

    bf16x8 hreg[13];
    const __bf16* hsrc = hprev + (size_t)bL * HROW + dcol;
#pragma unroll
    for (int i = 0; i < 12; ++i)
      hreg[i] = *(const bf16x8*)(hsrc + (i * 8 + w * 2 + gl) * 8);
    if (w < 2) hreg[12] = *(const bf16x8*)(hsrc + (96 + w * 2 + gl) * 8);
    bf16x8 xv = *(const bf16x8*)(A.xpad + ((size_t)tt * BT + bL) * 64 + (tid >> 5) * 8);

#pragma unroll
    for (int i = 0; i < 12; ++i)
      *(bf16x8*)(u2 + (size_t)(i * 8 + w * 2 + gl) * 256 + bL * 8) = hreg[i];
    if (w < 2)
      *(bf16x8*)(u2 + (size_t)(96 + w * 2 + gl) * 256 + bL * 8) = hreg[12];
    *(bf16x8*)(u2 + (size_t)(100 + (tid >> 5)) * 256 + bL * 8) = xv;
    __syncthreads();

    f32x4 acc0 = {0.f, 0.f, 0.f, 0.f}, acc1 = {0.f, 0.f, 0.f, 0.f};
#pragma unroll
    for (int sl = 0; sl < 27; ++sl) {
      bf16x8 bfr;
      if (sl < 25)
        bfr = *(const bf16x8*)(wlds + ((size_t)(w * 25 + sl) * 64 + l) * 8);
      else
        bfr = (sl == 25) ? wx_r0 : wx_r1;
      const __bf16* ab = u2 + (size_t)(sl * 4 + q) * 256 + nidx * 8;
      bf16x8 a0 = *(const bf16x8*)ab;
      bf16x8 a1 = *(const bf16x8*)(ab + 128);
      acc0 = mfma16(a0, bfr, acc0);
      acc1 = mfma16(a1, bfr, acc1);
    }
    __syncthreads();

#pragma unroll
    for (int r = 0; r < 4; ++r) {
      g_lds[w * 512 + (q * 4 + r) * 16 + nidx]      = acc0[r] + bias_n;
      g_lds[w * 512 + (16 + q * 4 + r) * 16 + nidx] = acc1[r] + bias_n;
    }
    __syncthreads();

    {
      const int uA = 2 * up, uB = uA + 1;
      float iA = g_lds[0 * 512 + bb * 16 + uA], fA = g_lds[1 * 512 + bb * 16 + uA];
      float gA = g_lds[2 * 512 + bb * 16 + uA], oA = g_lds[3 * 512 + bb * 16 + uA];
      cA = sigf(fA) * cA + sigf(iA) * tanhf(gA);
      float hA = sigf(oA) * tanhf(cA);
      float iB = g_lds[0 * 512 + bb * 16 + uB], fB = g_lds[1 * 512 + bb * 16 + uB];
      float gB = g_lds[2 * 512 + bb * 16 + uB], oB = g_lds[3 * 512 + bb * 16 + uB];
      cB = sigf(fB) * cB + sigf(iB) * tanhf(gB);
      float hB = sigf(oB) * tanhf(cB);
      union { u32 u; __bf16 h2[2]; } pk;
      pk.h2[0] = (__bf16)hA;
      pk.h2[1] = (__bf16)hB;
      ASTORE((u32*)(A.h0 + ((size_t)tt * BT + bb) * HROW + dcol + u0 + uA), pk.u);
    }

    if (s < TT - 1) rec_barrier(A.flags, (unsigned)(s + 1), d * 50, 50);
  }
}

// ---------------- xg1 chunk GEMM: xg1 = Wih1*h0[t] + b1 ----------------
struct GMArgs {
  const __bf16* h0;
  const float *Wih1f, *Wih1b, *b1f, *b1b;
  __bf16* xg;
  int k0;
};

__global__ __launch_bounds__(256, 1) void gemm_xg1(GMArgs A) {
  extern __shared__ __bf16 u[];   // 200 groups x [32 b][8]
  const int tid = threadIdx.x, w = tid >> 6, l = tid & 63;
  const int nidx = l & 15, q = l >> 4;
  const int j = blockIdx.x, d = j / CH, tloc = j % CH;
  const int rb = blockIdx.y;
  const int t = d ? (TT - 1 - A.k0 - tloc) : (A.k0 + tloc);

  const int bq = tid >> 3, go = tid & 7;
  for (int g = go; g < 200; g += 8) {
    const int pc = g * 8 + (g >= 100 ? 32 : 0);   // logical->physical h0 col
    bf16x8 v = *(const bf16x8*)(A.h0 + ((size_t)t * BT + bq) * HROW + pc);
    *(bf16x8*)(u + (size_t)g * 256 + bq * 8) = v;
  }
  __syncthreads();

  const int row = rb * 64 + w * 16 + nidx;
  const float* wr = (d ? A.Wih1b : A.Wih1f) + (size_t)row * 1600 + q * 8;
  f32x4 acc0 = {0.f, 0.f, 0.f, 0.f}, acc1 = {0.f, 0.f, 0.f, 0.f};
#pragma unroll
  for (int sl = 0; sl < 50; ++sl) {
    f32x4 wa = *(const f32x4*)(wr + sl * 32);
    f32x4 wb = *(const f32x4*)(wr + sl * 32 + 4);
    bf16x8 bfr = cvt8(wa, wb);
    const __bf16* ab = u + (size_t)(sl * 4 + q) * 256 + nidx * 8;
    bf16x8 a0 = *(const bf16x8*)ab;
    bf16x8 a1 = *(const bf16x8*)(ab + 128);
    acc0 = mfma16(a0, bfr, acc0);
    acc1 = mfma16(a1, bfr, acc1);
  }
  const float bn = (d ? A.b1b : A.b1f)[row];
  __bf16* op = A.xg + ((size_t)(d * CH + tloc) * 3200 + row) * 32 + q * 4;
  bf16x4 v0, v1;
#pragma unroll
  for (int r = 0; r < 4; ++r) {
    v0[r] = (__bf16)(acc0[r] + bn);
    v1[r] = (__bf16)(acc1[r] + bn);
  }
  *(bf16x4*)op = v0;
  *(bf16x4*)(op + 16) = v1;
}

// ---------------- L1 persistent recurrence (one chunk) ----------------
struct L1Args {
  const __bf16 *xg, *zero;
  const float *Whh1f, *Whh1b;
  __bf16* h1;
  float* cst;
  u32* flags;
  int s0;
};

__global__ __launch_bounds__(256, 1) void lstm_l1(L1Args A) {
  extern __shared__ __bf16 u2[];
  const int wg = blockIdx.x, d = wg / 50, u0 = (wg % 50) * 16;
  const int tid = threadIdx.x, w = tid >> 6, l = tid & 63;
  const int nidx = l & 15, q = l >> 4, bL = l & 31, gl = l >> 5;
  const int dcol = d * 832;
  const int row = w * 800 + u0 + nidx;
  const float* wrf = (d ? A.Whh1b : A.Whh1f) + (size_t)row * 800 + q * 8;
  __bf16* wlds = u2 + 100 * 256;
  float* g_lds = (float*)u2;
  const int bb = tid >> 3, up = tid & 7;

#pragma unroll
  for (int sl = 0; sl < 25; ++sl) {
    f32x4 wa = *(const f32x4*)(wrf + sl * 32);
    f32x4 wb = *(const f32x4*)(wrf + sl * 32 + 4);
    *(bf16x8*)(wlds + ((size_t)(w * 25 + sl) * 64 + l) * 8) = cvt8(wa, wb);
  }
  float cA = 0.f, cB = 0.f;
  float* cp = A.cst + ((size_t)d * 32 + bb) * 800 + u0 + 2 * up;
  if (A.s0 > 0) { cA = cp[0]; cB = cp[1]; }
  __syncthreads();

#pragma unroll 1
  for (int si = 0; si < CH; ++si) {
    const int s = A.s0 + si;
    const int tt = d ? (TT - 1 - s) : s;
    const __bf16* hprev =
        (s == 0) ? A.zero : (A.h1 + (size_t)(d ? tt + 1 : tt - 1) * (BT * HROW));

    // xg -> accumulator init (bias already folded in)
    const __bf16* xgp = A.xg + ((size_t)(d * CH + si) * 3200 + row) * 32 + q * 4;
    bf16x4 xa = *(const bf16x4*)xgp;
    bf16x4 xb = *(const bf16x4*)(xgp + 16);
    f32x4 acc0 = {(float)xa[0], (float)xa[1], (float)xa[2], (float)xa[3]};
    f32x4 acc1 = {(float)xb[0], (float)xb[1], (float)xb[2], (float)xb[3]};

    bf16x8 hreg[13];
    const __bf16* hsrc = hprev + (size_t)bL * HROW + dcol;
#pragma unroll
    for (int i = 0; i < 12; ++i)
      hreg[i] = *(const bf16x8*)(hsrc + (i * 8 + w * 2 + gl) * 8);
    if (w < 2) hreg[12] = *(const bf16x8*)(hsrc + (96 + w * 2 + gl) * 8);

#pragma unroll
    for (int i = 0; i < 12; ++i)
      *(bf16x8*)(u2 + (size_t)(i * 8 + w * 2 + gl) * 256 + bL * 8) = hreg[i];
    if (w < 2)
      *(bf16x8*)(u2 + (size_t)(96 + w * 2 + gl) * 256 + bL * 8) = hreg[12];
    __syncthreads();

#pragma unroll
    for (int sl = 0; sl < 25; ++sl) {
      bf16x8 bfr = *(const bf16x8*)(wlds + ((size_t)(w * 25 + sl) * 64 + l) * 8);
      const __bf16* ab = u2 + (size_t)(sl * 4 + q) * 256 + nidx * 8;
      bf16x8 a0 = *(const bf16x8*)ab;
      bf16x8 a1 = *(const bf16x8*)(ab + 128);
      acc0 = mfma16(a0, bfr, acc0);
      acc1 = mfma16(a1, bfr, acc1);
    }
    __syncthreads();

#pragma unroll
    for (int r = 0; r < 4; ++r) {
      g_lds[w * 512 + (q * 4 + r) * 16 + nidx]      = acc0[r];
      g_lds[w * 512 + (16 + q * 4 + r) * 16 + nidx] = acc1[r];
    }
    __syncthreads();

    {
      const int uA = 2 * up, uB = uA + 1;
      float iA = g_lds[0 * 512 + bb * 16 + uA], fA = g_lds[1 * 512 + bb * 16 + uA];
      float gA = g_lds[2 * 512 + bb * 16 + uA], oA = g_lds[3 * 512 + bb * 16 + uA];
      cA = sigf(fA) * cA + sigf(iA) * tanhf(gA);
      float hA = sigf(oA) * tanhf(cA);
      float iB = g_lds[0 * 512 + bb * 16 + uB], fB = g_lds[1 * 512 + bb * 16 + uB];
      float gB = g_lds[2 * 512 + bb * 16 + uB], oB = g_lds[3 * 512 + bb * 16 + uB];
      cB = sigf(fB) * cB + sigf(iB) * tanhf(gB);
      float hB = sigf(oB) * tanhf(cB);
      union { u32 u; __bf16 h2[2]; } pk;
      pk.h2[0] = (__bf16)hA;
      pk.h2[1] = (__bf16)hB;
      ASTORE((u32*)(A.h1 + ((size_t)tt * BT + bb) * HROW + dcol + u0 + uA), pk.u);
    }

    if (si < CH - 1) rec_barrier(A.flags, (unsigned)(s + 1), d * 50, 50);
  }
  if (A.s0 + CH < TT) { cp[0] = cA; cp[1] = cB; }
}

// ---------------- FC + softmax + dihedral -> points ----------------
__global__ __launch_bounds__(256) void fc_kernel(
    const __bf16* __restrict__ h1, const __bf16* __restrict__ xpad,
    const __bf16* __restrict__ wfc, const float* __restrict__ fcb,
    const float* __restrict__ sinA, const float* __restrict__ cosA,
    float* __restrict__ pts) {
  __shared__ float lg[32 * 64];
  const int t = blockIdx.x, tid = threadIdx.x;
  const int wave = tid >> 6, lane = tid & 63, nidx = lane & 15, q = lane >> 4;
  const int a_col = wave * 16 + nidx;
  const __bf16* wrow = wfc + (size_t)a_col * 1664 + q * 8;
  const __bf16* h1row = h1 + (size_t)t * BT * HROW;
  const __bf16* xrow  = xpad + (size_t)t * BT * 64;
  f32x4 acc0 = {0.f, 0.f, 0.f, 0.f}, acc1 = {0.f, 0.f, 0.f, 0.f};
#pragma unroll
  for (int sl = 0; sl < 52; ++sl) {
    const int k = sl * 32 + q * 8;
    bf16x8 a0, a1;
    if (sl < 50) {
      const int kp = (sl < 25) ? k : (k + 32);
      a0 = *(const bf16x8*)(h1row + (size_t)nidx * HROW + kp);
      a1 = *(const bf16x8*)(h1row + (size_t)(16 + nidx) * HROW + kp);
    } else {
      a0 = *(const bf16x8*)(xrow + nidx * 64 + (k - 1600));
      a1 = *(const bf16x8*)(xrow + (16 + nidx) * 64 + (k - 1600));
    }
    bf16x8 bfr = *(const bf16x8*)(wrow + sl * 32);
    acc0 = mfma16(a0, bfr, acc0);
    acc1 = mfma16(a1, bfr, acc1);
  }
  const float bn = (a_col < 60) ? fcb[a_col] : -1e30f;
#pragma unroll
  for (int r = 0; r < 4; ++r) {
    lg[(q * 4 + r) * 64 + a_col]      = acc0[r] + bn;
    lg[(16 + q * 4 + r) * 64 + a_col] = acc1[r] + bn;
  }
  __syncthreads();

  const int b = tid >> 3, j = tid & 7;
  float v[8];
  float m = -1e30f;
#pragma unroll
  for (int k2 = 0; k2 < 8; ++k2) {
    v[k2] = lg[b * 64 + j + 8 * k2];
    m = fmaxf(m, v[k2]);
  }
  m = fmaxf(m, __shfl_xor(m, 1, 8));
  m = fmaxf(m, __shfl_xor(m, 2, 8));
  m = fmaxf(m, __shfl_xor(m, 4, 8));
  float s = 0.f;
#pragma unroll
  for (int k2 = 0; k2 < 8; ++k2) { v[k2] = __expf(v[k2] - m); s += v[k2]; }
  s += __shfl_xor(s, 1, 8);
  s += __shfl_xor(s, 2, 8);
  s += __shfl_xor(s, 4, 8);
  const float inv = 1.f / s;
  float ps[3] = {0.f, 0.f, 0.f}, pc[3] = {0.f, 0.f, 0.f};
#pragma unroll
  for (int k2 = 0; k2 < 8; ++k2) {
    const int a = j + 8 * k2;
    const float p = v[k2] * inv;
#pragma unroll
    for (int c = 0; c < 3; ++c) {
      ps[c] += p * sinA[a * 3 + c];
      pc[c] += p * cosA[a * 3 + c];
    }
  }
#pragma unroll
  for (int c = 0; c < 3; ++c) {
    ps[c] += __shfl_xor(ps[c], 1, 8);
    ps[c] += __shfl_xor(ps[c], 2, 8);
    ps[c] += __shfl_xor(ps[c], 4, 8);
    pc[c] += __shfl_xor(pc[c], 1, 8);
    pc[c] += __shfl_xor(pc[c], 2, 8);
    pc[c] += __shfl_xor(pc[c], 4, 8);
  }
  if (j == 0) {
    const float BL[3] = {145.801f, 152.326f, 132.868f};
    const float BA[3] = {2.124f, 1.941f, 2.028f};
#pragma unroll
    for (int c = 0; c < 3; ++c) {
      const float ang = 3.14159265358979323846f - BA[c];
      const float rct = BL[c] * cosf(ang), rst = BL[c] * sinf(ang);
      const float dih = atan2f(ps[c], pc[c]);
      float* o = pts + ((size_t)(3 * t + c) * BT + b) * 3;
      o[0] = rct;
      o[1] = cosf(dih) * rst;
      o[2] = sinf(dih) * rst;
    }
  }
}

// ---------------- sequential NeRF extension ----------------
__global__ void nerf_kernel(const float* __restrict__ pts, float* __restrict__ out) {
  const int b = threadIdx.x;
  if (b >= 32) return;
  float ax = -0.70710678f, ay = 1.22474487f, az = 0.f;
  float bx = -1.41421356f, by = 0.f, bz = 0.f;
  float cx = 0.f, cy = 0.f, cz = 0.f;
#pragma unroll 4
  for (int i = 0; i < 3 * TT; ++i) {
    const float* p = pts + ((size_t)i * BT + b) * 3;
    const float p0 = p[0], p1 = p[1], p2 = p[2];
    float ux = cx - bx, uy = cy - by, uz = cz - bz;
    const float ri = rsqrtf(ux * ux + uy * uy + uz * uz + 1e-12f);
    ux *= ri; uy *= ri; uz *= ri;
    const float wx = bx - ax, wy = by - ay, wz = bz - az;
    float nx = wy * uz - wz * uy, ny = wz * ux - wx * uz, nz = wx * uy - wy * ux;
    const float rn = rsqrtf(nx * nx + ny * ny + nz * nz + 1e-12f);
    nx *= rn; ny *= rn; nz *= rn;
    const float mx = ny * uz - nz * uy, my = nz * ux - nx * uz, mz = nx * uy - ny * ux;
    const float ox = cx + p0 * ux + p1 * mx + p2 * nx;
    const float oy = cy + p0 * uy + p1 * my + p2 * ny;
    const float oz = cz + p0 * uz + p1 * mz + p2 * nz;
    out[((size_t)i * BT + b) * 3 + 0] = ox;
    out[((size_t)i * BT + b) * 3 + 1] = oy;
    out[((size_t)i * BT + b) * 3 + 2] = oz;
    ax = bx; ay = by; az = bz;
    bx = cx; by = cy; bz = cz;
    cx = ox; cy = oy; cz = oz;
  }
}

// ---------------- launch ----------------
extern "C" void kernel_launch(void* const* d_in, const int* in_sizes, int n_in,
                              void* d_out, int out_size, void* d_ws, size_t ws_size,
                              hipStream_t stream) {
  (void)in_sizes; (void)n_in; (void)out_size;
  const int*   primary = (const int*)d_in[0];
  const float* evo     = (const float*)d_in[1];
  const float* emb     = (const float*)d_in[3];
  const float* Wih0f   = (const float*)d_in[4];
  const float* Whh0f   = (const float*)d_in[5];
  const float* b0f     = (const float*)d_in[6];
  const float* Wih0b   = (const float*)d_in[7];
  const float* Whh0b   = (const float*)d_in[8];
  const float* b0b     = (const float*)d_in[9];
  const float* Wih1f   = (const float*)d_in[10];
  const float* Whh1f   = (const float*)d_in[11];
  const float* b1f     = (const float*)d_in[12];
  const float* Wih1b   = (const float*)d_in[13];
  const float* Whh1b   = (const float*)d_in[14];
  const float* b1b     = (const float*)d_in[15];
  const float* fcW     = (const float*)d_in[16];
  const float* fcb     = (const float*)d_in[17];
  const float* alpha   = (const float*)d_in[18];

  char* ws = (char*)d_ws;
  size_t off = 0;
  auto take = [&](size_t n) -> void* {
    void* p = ws + off;
    off += (n + 511) & ~(size_t)511;
    return p;
  };
  __bf16* xpad = (__bf16*)take((size_t)TT * BT * 64 * 2);        // 2.87 MB
  __bf16* zb   = (__bf16*)take((size_t)BT * HROW * 2);           // 106 KB
  __bf16* wx0  = (__bf16*)take((size_t)2 * 3200 * 64 * 2);       // 819 KB
  __bf16* wfc  = (__bf16*)take((size_t)64 * 1664 * 2);           // 213 KB
  float*  sinA = (float*)take(192 * 4);
  float*  cosA = (float*)take(192 * 4);
  float*  pts  = (float*)take((size_t)3 * TT * BT * 3 * 4);      // 806 KB
  u32*    flags0 = (u32*)take(6400 * 4);                         // 25.6 KB (both arrays)
  u32*    flags1 = flags0 + 3200;
  float*  cst  = (float*)take((size_t)2 * 32 * 800 * 4);         // 205 KB
  __bf16* xg1  = (__bf16*)take((size_t)2 * CH * 3200 * 32 * 2);  // 20.5 MB
  __bf16* h0   = (__bf16*)take((size_t)TT * BT * HROW * 2);      // 74.5 MB
  __bf16* h1   = (__bf16*)take((size_t)TT * BT * HROW * 2);      // 74.5 MB
  if (off > ws_size) return;  // failure signature: absmax == max|ref| == 233472

  static int lds_cfg = 0;
  if (!lds_cfg) {   // first (non-captured) call configures; replays skip
    hipFuncSetAttribute((const void*)lstm_l0,
                        hipFuncAttributeMaxDynamicSharedMemorySize, LDS_L0);
    hipFuncSetAttribute((const void*)lstm_l1,
                        hipFuncAttributeMaxDynamicSharedMemorySize, LDS_L1);
    hipFuncSetAttribute((const void*)gemm_xg1,
                        hipFuncAttributeMaxDynamicSharedMemorySize, LDS_GM);
    lds_cfg = 1;
  }

  pack_wx0_kernel<<<1600, 256, 0, stream>>>(Wih0f, Wih0b, wx0);
  pack_fc_kernel<<<(64 * 1664 + 255) / 256, 256, 0, stream>>>(fcW, wfc);
  xpad_kernel<<<(TT * BT * 64) / 256, 256, 0, stream>>>(primary, evo, emb, xpad);
  small_init_kernel<<<209, 256, 0, stream>>>(zb, flags0, sinA, cosA, alpha);

  L0Args a0;
  a0.xpad = xpad; a0.wx0 = wx0; a0.zero = zb;
  a0.Whh0f = Whh0f; a0.Whh0b = Whh0b; a0.b0f = b0f; a0.b0b = b0b;
  a0.h0 = h0; a0.flags = flags0;
  lstm_l0<<<NWG, 256, LDS_L0, stream>>>(a0);

  for (int k = 0; k < TT / CH; ++k) {
    GMArgs g;
    g.h0 = h0; g.Wih1f = Wih1f; g.Wih1b = Wih1b; g.b1f = b1f; g.b1b = b1b;
    g.xg = xg1; g.k0 = k * CH;
    gemm_xg1<<<dim3(2 * CH, 50), 256, LDS_GM, stream>>>(g);

    L1Args a1;
    a1.xg = xg1; a1.zero = zb;
    a1.Whh1f = Whh1f; a1.Whh1b = Whh1b;
    a1.h1 = h1; a1.cst = cst; a1.flags = flags1; a1.s0 = k * CH;
    lstm_l1<<<NWG, 256, LDS_L1, stream>>>(a1);
  }

  fc_kernel<<<TT, 256, 0, stream>>>(h1, xpad, wfc, fcb, sinA, cosA, pts);
  nerf_kernel<<<1, 64, 0, stream>>>(pts, (float*)d_out);
}

// Round 9
// 11486.963 us; speedup vs baseline: 1.9564x; 1.1473x over previous
//
#include <hip/hip_runtime.h>
#include <hip/hip_bf16.h>
#include <math.h>

// ---------------------------------------------------------------------------
// RGN model: T=700 B=32 H=800 EMB=32 EVO=21 A=60
// f32 in / f32 out; internal bf16 MFMA.
// L0: persistent recurrence, Whh0 LDS-resident.
// L1: xg1 = Wih1*h0 + b1 by chunked GEMM with LDS-stationary weights
//     (200 blocks, t-inner loop), interleaved with persistent recurrence
//     launches (Whh1 LDS-resident, c-state spilled). Flag barriers.
// ---------------------------------------------------------------------------

typedef unsigned int u32;
typedef __bf16 bf16x8 __attribute__((ext_vector_type(8)));
typedef __bf16 bf16x4 __attribute__((ext_vector_type(4)));
typedef float  f32x4  __attribute__((ext_vector_type(4)));

#define TT 700
#define BT 32
#define HROW 1664          // 800 fwd | 32 pad | 800 bwd | 32 pad
#define NWG 100
#define CH 50              // L1 chunk length (14 chunks)
#define LDS_L0 (108 * 512 + 102400)   // 157,696 B
#define LDS_L1 (100 * 512 + 102400)   // 153,600 B
#define LDS_GM 102400                 // 100 groups x 1024 B (32 rows x 1600 bf16)

__device__ __forceinline__ f32x4 mfma16(bf16x8 a, bf16x8 b, f32x4 c) {
  return __builtin_amdgcn_mfma_f32_16x16x32_bf16(a, b, c, 0, 0, 0);
}
__device__ __forceinline__ float sigf(float x) { return 1.f / (1.f + __expf(-x)); }

#define ALOAD(p)    __hip_atomic_load((p), __ATOMIC_RELAXED, __HIP_MEMORY_SCOPE_AGENT)
#define ASTORE(p,v) __hip_atomic_store((p), (v), __ATOMIC_RELAXED, __HIP_MEMORY_SCOPE_AGENT)

__device__ __forceinline__ bf16x8 cvt8(f32x4 a, f32x4 b) {
  bf16x8 r;
  r[0] = (__bf16)a[0]; r[1] = (__bf16)a[1]; r[2] = (__bf16)a[2]; r[3] = (__bf16)a[3];
  r[4] = (__bf16)b[0]; r[5] = (__bf16)b[1]; r[6] = (__bf16)b[2]; r[7] = (__bf16)b[3];
  return r;
}

// ---------------- pack / init kernels ----------------
__global__ void pack_wx0_kernel(const float* Wih0f, const float* Wih0b, __bf16* wx0) {
  int idx = blockIdx.x * 256 + threadIdx.x;      // 2*3200*64 exact
  if (idx >= 2 * 3200 * 64) return;
  int d = idx / (3200 * 64);
  int r = (idx / 64) % 3200;
  int k = idx % 64;
  const float* W = d ? Wih0b : Wih0f;
  wx0[idx] = (k < 53) ? (__bf16)W[(size_t)r * 53 + k] : (__bf16)0.f;
}

__global__ void pack_fc_kernel(const float* fcW, __bf16* wfc) {
  int idx = blockIdx.x * 256 + threadIdx.x;
  if (idx >= 64 * 1664) return;
  int a = idx / 1664, k = idx % 1664;
  __bf16 v = (__bf16)0.f;
  if (a < 60 && k < 1653) v = (__bf16)fcW[(size_t)a * 1653 + k];
  wfc[idx] = v;
}

__global__ void xpad_kernel(const int* primary, const float* evo,
                            const float* emb, __bf16* xpad) {
  int idx = blockIdx.x * 256 + threadIdx.x;   // 700*32*64 exact
  int t = idx >> 11;
  int b = (idx >> 6) & 31;
  int k = idx & 63;
  __bf16 v = (__bf16)0.f;
  if (k < 32)      v = (__bf16)emb[primary[t * 32 + b] * 32 + k];
  else if (k < 53) v = (__bf16)evo[((size_t)t * 32 + b) * 21 + (k - 32)];
  xpad[idx] = v;
}

__global__ void small_init_kernel(__bf16* zerobuf, u32* flags,
                                  float* sinA, float* cosA, const float* alpha) {
  int idx = blockIdx.x * 256 + threadIdx.x;
  if (idx < 32 * HROW) zerobuf[idx] = (__bf16)0.f;
  if (idx < 6400) flags[idx] = 0u;
  int j = idx - 32 * HROW;
  if (j >= 0 && j < 192) {
    if (j < 180) {
      float v = alpha[j];
      sinA[j] = sinf(v);
      cosA[j] = cosf(v);
    } else { sinA[j] = 0.f; cosA[j] = 0.f; }
  }
}

// ---------------- barrier ----------------
__device__ __forceinline__ void rec_barrier(u32* flags, unsigned gen,
                                            int base, int count) {
  asm volatile("s_waitcnt vmcnt(0)" ::: "memory");
  __syncthreads();
  const int tid = threadIdx.x;
  if (tid == 0) ASTORE(flags + (size_t)blockIdx.x * 32, gen);
  if (tid < 64) {
    int spin = 0;
    for (;;) {
      bool ok = true;
      for (int j = tid; j < count; j += 64)
        ok = ok && (ALOAD(flags + (size_t)(base + j) * 32) >= gen);
      if (__popcll(__ballot(ok)) == 64) break;
      if (++spin > 24) __builtin_amdgcn_s_sleep(1);
    }
  }
  __syncthreads();
}

// ---------------- L0 persistent recurrence ----------------
struct L0Args {
  const __bf16 *xpad, *wx0, *zero;
  const float *Whh0f, *Whh0b, *b0f, *b0b;
  __bf16* h0;
  u32* flags;
};

__global__ __launch_bounds__(256, 1) void lstm_l0(L0Args A) {
  extern __shared__ __bf16 u2[];
  const int wg = blockIdx.x, d = wg / 50, u0 = (wg % 50) * 16;
  const int tid = threadIdx.x, w = tid >> 6, l = tid & 63;
  const int nidx = l & 15, q = l >> 4, bL = l & 31, gl = l >> 5;
  const int dcol = d * 832;
  const int row = w * 800 + u0 + nidx;
  const float bias_n = (d ? A.b0b : A.b0f)[row];
  const float* wrf = (d ? A.Whh0b : A.Whh0f) + (size_t)row * 800 + q * 8;
  __bf16* wlds = u2 + 108 * 256;
  float* g_lds = (float*)u2;
  const int bb = tid >> 3, up = tid & 7;

#pragma unroll
  for (int sl = 0; sl < 25; ++sl) {
    f32x4 wa = *(const f32x4*)(wrf + sl * 32);
    f32x4 wb = *(const f32x4*)(wrf + sl * 32 + 4);
    *(bf16x8*)(wlds + ((size_t)(w * 25 + sl) * 64 + l) * 8) = cvt8(wa, wb);
  }
  const __bf16* wx_row = A.wx0 + (size_t)d * 3200 * 64 + (size_t)row * 64 + q * 8;
  bf16x8 wx_r0 = *(const bf16x8*)wx_row;
  bf16x8 wx_r1 = *(const bf16x8*)(wx_row + 32);
  __syncthreads();

  float cA = 0.f, cB = 0.f;
#pragma unroll 1
  for (int s = 0; s < TT; ++s) {
    const int tt = d ? (TT - 1 - s) : s;
    const __bf16* hprev =
        (s == 0) ? A.zero : (A.h0 + (size_t)(d ? tt + 1 : tt - 1) * (BT * HROW));

    bf16x8 hreg[13];
    const __bf16* hsrc = hprev + (size_t)bL * HROW + dcol;
#pragma unroll
    for (int i = 0; i < 12; ++i)
      hreg[i] = *(const bf16x8*)(hsrc + (i * 8 + w * 2 + gl) * 8);
    if (w < 2) hreg[12] = *(const bf16x8*)(hsrc + (96 + w * 2 + gl) * 8);
    bf16x8 xv = *(const bf16x8*)(A.xpad + ((size_t)tt * BT + bL) * 64 + (tid >> 5) * 8);

#pragma unroll
    for (int i = 0; i < 12; ++i)
      *(bf16x8*)(u2 + (size_t)(i * 8 + w * 2 + gl) * 256 + bL * 8) = hreg[i];
    if (w < 2)
      *(bf16x8*)(u2 + (size_t)(96 + w * 2 + gl) * 256 + bL * 8) = hreg[12];
    *(bf16x8*)(u2 + (size_t)(100 + (tid >> 5)) * 256 + bL * 8) = xv;
    __syncthreads();

    f32x4 acc0 = {0.f, 0.f, 0.f, 0.f}, acc1 = {0.f, 0.f, 0.f, 0.f};
#pragma unroll
    for (int sl = 0; sl < 27; ++sl) {
      bf16x8 bfr;
      if (sl < 25)
        bfr = *(const bf16x8*)(wlds + ((size_t)(w * 25 + sl) * 64 + l) * 8);
      else
        bfr = (sl == 25) ? wx_r0 : wx_r1;
      const __bf16* ab = u2 + (size_t)(sl * 4 + q) * 256 + nidx * 8;
      bf16x8 a0 = *(const bf16x8*)ab;
      bf16x8 a1 = *(const bf16x8*)(ab + 128);
      acc0 = mfma16(a0, bfr, acc0);
      acc1 = mfma16(a1, bfr, acc1);
    }
    __syncthreads();

#pragma unroll
    for (int r = 0; r < 4; ++r) {
      g_lds[w * 512 + (q * 4 + r) * 16 + nidx]      = acc0[r] + bias_n;
      g_lds[w * 512 + (16 + q * 4 + r) * 16 + nidx] = acc1[r] + bias_n;
    }
    __syncthreads();

    {
      const int uA = 2 * up, uB = uA + 1;
      float iA = g_lds[0 * 512 + bb * 16 + uA], fA = g_lds[1 * 512 + bb * 16 + uA];
      float gA = g_lds[2 * 512 + bb * 16 + uA], oA = g_lds[3 * 512 + bb * 16 + uA];
      cA = sigf(fA) * cA + sigf(iA) * tanhf(gA);
      float hA = sigf(oA) * tanhf(cA);
      float iB = g_lds[0 * 512 + bb * 16 + uB], fB = g_lds[1 * 512 + bb * 16 + uB];
      float gB = g_lds[2 * 512 + bb * 16 + uB], oB = g_lds[3 * 512 + bb * 16 + uB];
      cB = sigf(fB) * cB + sigf(iB) * tanhf(gB);
      float hB = sigf(oB) * tanhf(cB);
      union { u32 u; __bf16 h2[2]; } pk;
      pk.h2[0] = (__bf16)hA;
      pk.h2[1] = (__bf16)hB;
      ASTORE((u32*)(A.h0 + ((size_t)tt * BT + bb) * HROW + dcol + u0 + uA), pk.u);
    }

    if (s < TT - 1) rec_barrier(A.flags, (unsigned)(s + 1), d * 50, 50);
  }
}

// ---------------- xg1 chunk GEMM: weights LDS-stationary, t inner ----------
struct GMArgs {
  const __bf16* h0;
  const float *Wih1f, *Wih1b, *b1f, *b1b;
  __bf16* xg;
  int k0;
};

__global__ __launch_bounds__(256, 1) void gemm_xg1(GMArgs A) {
  extern __shared__ __bf16 wl[];   // [(rh*50+sl)][lane][8] = 32 rows x 1600 bf16
  const int tid = threadIdx.x, w = tid >> 6, l = tid & 63;
  const int nidx = l & 15, q = l >> 4;
  const int rb = blockIdx.x;       // 0..99: 32 gate-rows each
  const int d  = blockIdx.y;
  const float* W = d ? A.Wih1b : A.Wih1f;

  // stage this block's 32 rows of Wih1 (f32 -> bf16) once
#pragma unroll
  for (int i = w * 25; i < w * 25 + 25; ++i) {
    const int rh = i / 50, sl = i % 50;
    const int row = rb * 32 + rh * 16 + nidx;
    const float* wp = W + (size_t)row * 1600 + sl * 32 + q * 8;
    f32x4 wa = *(const f32x4*)wp;
    f32x4 wb = *(const f32x4*)(wp + 4);
    *(bf16x8*)(wl + ((size_t)i * 64 + l) * 8) = cvt8(wa, wb);
  }
  __syncthreads();

  const int rh = w >> 1, bh = w & 1;          // wave tile: (row-half, batch-half)
  const int row = rb * 32 + rh * 16 + nidx;
  const float bn = (d ? A.b1b : A.b1f)[row];

#pragma unroll 1
  for (int tloc = 0; tloc < CH; ++tloc) {
    const int t = d ? (TT - 1 - A.k0 - tloc) : (A.k0 + tloc);
    const __bf16* hrow = A.h0 + ((size_t)t * BT + bh * 16 + nidx) * HROW;
    f32x4 acc = {0.f, 0.f, 0.f, 0.f};
#pragma unroll
    for (int sl = 0; sl < 50; ++sl) {
      const int pc = sl * 32 + (sl >= 25 ? 32 : 0) + q * 8;  // logical->physical
      bf16x8 a = *(const bf16x8*)(hrow + pc);
      bf16x8 b = *(const bf16x8*)(wl + ((size_t)(rh * 50 + sl) * 64 + l) * 8);
      acc = mfma16(a, b, acc);
    }
    bf16x4 v;
#pragma unroll
    for (int r = 0; r < 4; ++r) v[r] = (__bf16)(acc[r] + bn);
    *(bf16x4*)(A.xg + ((size_t)(d * CH + tloc) * 3200 + row) * 32 + bh * 16 + q * 4) = v;
  }
}

// ---------------- L1 persistent recurrence (one chunk) ----------------
struct L1Args {
  const __bf16 *xg, *zero;
  const float *Whh1f, *Whh1b;
  __bf16* h1;
  float* cst;
  u32* flags;
  int s0;
};

__global__ __launch_bounds__(256, 1) void lstm_l1(L1Args A) {
  extern __shared__ __bf16 u2[];
  const int wg = blockIdx.x, d = wg / 50, u0 = (wg % 50) * 16;
  const int tid = threadIdx.x, w = tid >> 6, l = tid & 63;
  const int nidx = l & 15, q = l >> 4, bL = l & 31, gl = l >> 5;
  const int dcol = d * 832;
  const int row = w * 800 + u0 + nidx;
  const float* wrf = (d ? A.Whh1b : A.Whh1f) + (size_t)row * 800 + q * 8;
  __bf16* wlds = u2 + 100 * 256;
  float* g_lds = (float*)u2;
  const int bb = tid >> 3, up = tid & 7;

#pragma unroll
  for (int sl = 0; sl < 25; ++sl) {
    f32x4 wa = *(const f32x4*)(wrf + sl * 32);
    f32x4 wb = *(const f32x4*)(wrf + sl * 32 + 4);
    *(bf16x8*)(wlds + ((size_t)(w * 25 + sl) * 64 + l) * 8) = cvt8(wa, wb);
  }
  float cA = 0.f, cB = 0.f;
  float* cp = A.cst + ((size_t)d * 32 + bb) * 800 + u0 + 2 * up;
  if (A.s0 > 0) { cA = cp[0]; cB = cp[1]; }
  __syncthreads();

#pragma unroll 1
  for (int si = 0; si < CH; ++si) {
    const int s = A.s0 + si;
    const int tt = d ? (TT - 1 - s) : s;
    const __bf16* hprev =
        (s == 0) ? A.zero : (A.h1 + (size_t)(d ? tt + 1 : tt - 1) * (BT * HROW));

    const __bf16* xgp = A.xg + ((size_t)(d * CH + si) * 3200 + row) * 32 + q * 4;
    bf16x4 xa = *(const bf16x4*)xgp;
    bf16x4 xb = *(const bf16x4*)(xgp + 16);
    f32x4 acc0 = {(float)xa[0], (float)xa[1], (float)xa[2], (float)xa[3]};
    f32x4 acc1 = {(float)xb[0], (float)xb[1], (float)xb[2], (float)xb[3]};

    bf16x8 hreg[13];
    const __bf16* hsrc = hprev + (size_t)bL * HROW + dcol;
#pragma unroll
    for (int i = 0; i < 12; ++i)
      hreg[i] = *(const bf16x8*)(hsrc + (i * 8 + w * 2 + gl) * 8);
    if (w < 2) hreg[12] = *(const bf16x8*)(hsrc + (96 + w * 2 + gl) * 8);

#pragma unroll
    for (int i = 0; i < 12; ++i)
      *(bf16x8*)(u2 + (size_t)(i * 8 + w * 2 + gl) * 256 + bL * 8) = hreg[i];
    if (w < 2)
      *(bf16x8*)(u2 + (size_t)(96 + w * 2 + gl) * 256 + bL * 8) = hreg[12];
    __syncthreads();

#pragma unroll
    for (int sl = 0; sl < 25; ++sl) {
      bf16x8 bfr = *(const bf16x8*)(wlds + ((size_t)(w * 25 + sl) * 64 + l) * 8);
      const __bf16* ab = u2 + (size_t)(sl * 4 + q) * 256 + nidx * 8;
      bf16x8 a0 = *(const bf16x8*)ab;
      bf16x8 a1 = *(const bf16x8*)(ab + 128);
      acc0 = mfma16(a0, bfr, acc0);
      acc1 = mfma16(a1, bfr, acc1);
    }
    __syncthreads();

#pragma unroll
    for (int r = 0; r < 4; ++r) {
      g_lds[w * 512 + (q * 4 + r) * 16 + nidx]      = acc0[r];
      g_lds[w * 512 + (16 + q * 4 + r) * 16 + nidx] = acc1[r];
    }
    __syncthreads();

    {
      const int uA = 2 * up, uB = uA + 1;
      float iA = g_lds[0 * 512 + bb * 16 + uA], fA = g_lds[1 * 512 + bb * 16 + uA];
      float gA = g_lds[2 * 512 + bb * 16 + uA], oA = g_lds[3 * 512 + bb * 16 + uA];
      cA = sigf(fA) * cA + sigf(iA) * tanhf(gA);
      float hA = sigf(oA) * tanhf(cA);
      float iB = g_lds[0 * 512 + bb * 16 + uB], fB = g_lds[1 * 512 + bb * 16 + uB];
      float gB = g_lds[2 * 512 + bb * 16 + uB], oB = g_lds[3 * 512 + bb * 16 + uB];
      cB = sigf(fB) * cB + sigf(iB) * tanhf(gB);
      float hB = sigf(oB) * tanhf(cB);
      union { u32 u; __bf16 h2[2]; } pk;
      pk.h2[0] = (__bf16)hA;
      pk.h2[1] = (__bf16)hB;
      ASTORE((u32*)(A.h1 + ((size_t)tt * BT + bb) * HROW + dcol + u0 + uA), pk.u);
    }

    if (si < CH - 1) rec_barrier(A.flags, (unsigned)(s + 1), d * 50, 50);
  }
  if (A.s0 + CH < TT) { cp[0] = cA; cp[1] = cB; }
}

// ---------------- FC + softmax + dihedral -> points ----------------
__global__ __launch_bounds__(256) void fc_kernel(
    const __bf16* __restrict__ h1, const __bf16* __restrict__ xpad,
    const __bf16* __restrict__ wfc, const float* __restrict__ fcb,
    const float* __restrict__ sinA, const float* __restrict__ cosA,
    float* __restrict__ pts) {
  __shared__ float lg[32 * 64];
  const int t = blockIdx.x, tid = threadIdx.x;
  const int wave = tid >> 6, lane = tid & 63, nidx = lane & 15, q = lane >> 4;
  const int a_col = wave * 16 + nidx;
  const __bf16* wrow = wfc + (size_t)a_col * 1664 + q * 8;
  const __bf16* h1row = h1 + (size_t)t * BT * HROW;
  const __bf16* xrow  = xpad + (size_t)t * BT * 64;
  f32x4 acc0 = {0.f, 0.f, 0.f, 0.f}, acc1 = {0.f, 0.f, 0.f, 0.f};
#pragma unroll
  for (int sl = 0; sl < 52; ++sl) {
    const int k = sl * 32 + q * 8;
    bf16x8 a0, a1;
    if (sl < 50) {
      const int kp = (sl < 25) ? k : (k + 32);
      a0 = *(const bf16x8*)(h1row + (size_t)nidx * HROW + kp);
      a1 = *(const bf16x8*)(h1row + (size_t)(16 + nidx) * HROW + kp);
    } else {
      a0 = *(const bf16x8*)(xrow + nidx * 64 + (k - 1600));
      a1 = *(const bf16x8*)(xrow + (16 + nidx) * 64 + (k - 1600));
    }
    bf16x8 bfr = *(const bf16x8*)(wrow + sl * 32);
    acc0 = mfma16(a0, bfr, acc0);
    acc1 = mfma16(a1, bfr, acc1);
  }
  const float bn = (a_col < 60) ? fcb[a_col] : -1e30f;
#pragma unroll
  for (int r = 0; r < 4; ++r) {
    lg[(q * 4 + r) * 64 + a_col]      = acc0[r] + bn;
    lg[(16 + q * 4 + r) * 64 + a_col] = acc1[r] + bn;
  }
  __syncthreads();

  const int b = tid >> 3, j = tid & 7;
  float v[8];
  float m = -1e30f;
#pragma unroll
  for (int k2 = 0; k2 < 8; ++k2) {
    v[k2] = lg[b * 64 + j + 8 * k2];
    m = fmaxf(m, v[k2]);
  }
  m = fmaxf(m, __shfl_xor(m, 1, 8));
  m = fmaxf(m, __shfl_xor(m, 2, 8));
  m = fmaxf(m, __shfl_xor(m, 4, 8));
  float s = 0.f;
#pragma unroll
  for (int k2 = 0; k2 < 8; ++k2) { v[k2] = __expf(v[k2] - m); s += v[k2]; }
  s += __shfl_xor(s, 1, 8);
  s += __shfl_xor(s, 2, 8);
  s += __shfl_xor(s, 4, 8);
  const float inv = 1.f / s;
  float ps[3] = {0.f, 0.f, 0.f}, pc[3] = {0.f, 0.f, 0.f};
#pragma unroll
  for (int k2 = 0; k2 < 8; ++k2) {
    const int a = j + 8 * k2;
    const float p = v[k2] * inv;
#pragma unroll
    for (int c = 0; c < 3; ++c) {
      ps[c] += p * sinA[a * 3 + c];
      pc[c] += p * cosA[a * 3 + c];
    }
  }
#pragma unroll
  for (int c = 0; c < 3; ++c) {
    ps[c] += __shfl_xor(ps[c], 1, 8);
    ps[c] += __shfl_xor(ps[c], 2, 8);
    ps[c] += __shfl_xor(ps[c], 4, 8);
    pc[c] += __shfl_xor(pc[c], 1, 8);
    pc[c] += __shfl_xor(pc[c], 2, 8);
    pc[c] += __shfl_xor(pc[c], 4, 8);
  }
  if (j == 0) {
    const float BL[3] = {145.801f, 152.326f, 132.868f};
    const float BA[3] = {2.124f, 1.941f, 2.028f};
#pragma unroll
    for (int c = 0; c < 3; ++c) {
      const float ang = 3.14159265358979323846f - BA[c];
      const float rct = BL[c] * cosf(ang), rst = BL[c] * sinf(ang);
      const float dih = atan2f(ps[c], pc[c]);
      float* o = pts + ((size_t)(3 * t + c) * BT + b) * 3;
      o[0] = rct;
      o[1] = cosf(dih) * rst;
      o[2] = sinf(dih) * rst;
    }
  }
}

// ---------------- sequential NeRF extension ----------------
__global__ void nerf_kernel(const float* __restrict__ pts, float* __restrict__ out) {
  const int b = threadIdx.x;
  if (b >= 32) return;
  float ax = -0.70710678f, ay = 1.22474487f, az = 0.f;
  float bx = -1.41421356f, by = 0.f, bz = 0.f;
  float cx = 0.f, cy = 0.f, cz = 0.f;
#pragma unroll 4
  for (int i = 0; i < 3 * TT; ++i) {
    const float* p = pts + ((size_t)i * BT + b) * 3;
    const float p0 = p[0], p1 = p[1], p2 = p[2];
    float ux = cx - bx, uy = cy - by, uz = cz - bz;
    const float ri = rsqrtf(ux * ux + uy * uy + uz * uz + 1e-12f);
    ux *= ri; uy *= ri; uz *= ri;
    const float wx = bx - ax, wy = by - ay, wz = bz - az;
    float nx = wy * uz - wz * uy, ny = wz * ux - wx * uz, nz = wx * uy - wy * ux;
    const float rn = rsqrtf(nx * nx + ny * ny + nz * nz + 1e-12f);
    nx *= rn; ny *= rn; nz *= rn;
    const float mx = ny * uz - nz * uy, my = nz * ux - nx * uz, mz = nx * uy - ny * ux;
    const float ox = cx + p0 * ux + p1 * mx + p2 * nx;
    const float oy = cy + p0 * uy + p1 * my + p2 * ny;
    const float oz = cz + p0 * uz + p1 * mz + p2 * nz;
    out[((size_t)i * BT + b) * 3 + 0] = ox;
    out[((size_t)i * BT + b) * 3 + 1] = oy;
    out[((size_t)i * BT + b) * 3 + 2] = oz;
    ax = bx; ay = by; az = bz;
    bx = cx; by = cy; bz = cz;
    cx = ox; cy = oy; cz = oz;
  }
}

// ---------------- launch ----------------
extern "C" void kernel_launch(void* const* d_in, const int* in_sizes, int n_in,
                              void* d_out, int out_size, void* d_ws, size_t ws_size,
                              hipStream_t stream) {
  (void)in_sizes; (void)n_in; (void)out_size;
  const int*   primary = (const int*)d_in[0];
  const float* evo     = (const float*)d_in[1];
  const float* emb     = (const float*)d_in[3];
  const float* Wih0f   = (const float*)d_in[4];
  const float* Whh0f   = (const float*)d_in[5];
  const float* b0f     = (const float*)d_in[6];
  const float* Wih0b   = (const float*)d_in[7];
  const float* Whh0b   = (const float*)d_in[8];
  const float* b0b     = (const float*)d_in[9];
  const float* Wih1f   = (const float*)d_in[10];
  const float* Whh1f   = (const float*)d_in[11];
  const float* b1f     = (const float*)d_in[12];
  const float* Wih1b   = (const float*)d_in[13];
  const float* Whh1b   = (const float*)d_in[14];
  const float* b1b     = (const float*)d_in[15];
  const float* fcW     = (const float*)d_in[16];
  const float* fcb     = (const float*)d_in[17];
  const float* alpha   = (const float*)d_in[18];

  char* ws = (char*)d_ws;
  size_t off = 0;
  auto take = [&](size_t n) -> void* {
    void* p = ws + off;
    off += (n + 511) & ~(size_t)511;
    return p;
  };
  __bf16* xpad = (__bf16*)take((size_t)TT * BT * 64 * 2);
  __bf16* zb   = (__bf16*)take((size_t)BT * HROW * 2);
  __bf16* wx0  = (__bf16*)take((size_t)2 * 3200 * 64 * 2);
  __bf16* wfc  = (__bf16*)take((size_t)64 * 1664 * 2);
  float*  sinA = (float*)take(192 * 4);
  float*  cosA = (float*)take(192 * 4);
  float*  pts  = (float*)take((size_t)3 * TT * BT * 3 * 4);
  u32*    flags0 = (u32*)take(6400 * 4);
  u32*    flags1 = flags0 + 3200;
  float*  cst  = (float*)take((size_t)2 * 32 * 800 * 4);
  __bf16* xg1  = (__bf16*)take((size_t)2 * CH * 3200 * 32 * 2);
  __bf16* h0   = (__bf16*)take((size_t)TT * BT * HROW * 2);
  __bf16* h1   = (__bf16*)take((size_t)TT * BT * HROW * 2);
  if (off > ws_size) return;  // failure signature: absmax == max|ref| == 233472

  static int lds_cfg = 0;
  if (!lds_cfg) {
    hipFuncSetAttribute((const void*)lstm_l0,
                        hipFuncAttributeMaxDynamicSharedMemorySize, LDS_L0);
    hipFuncSetAttribute((const void*)lstm_l1,
                        hipFuncAttributeMaxDynamicSharedMemorySize, LDS_L1);
    hipFuncSetAttribute((const void*)gemm_xg1,
                        hipFuncAttributeMaxDynamicSharedMemorySize, LDS_GM);
    lds_cfg = 1;
  }

  pack_wx0_kernel<<<1600, 256, 0, stream>>>(Wih0f, Wih0b, wx0);
  pack_fc_kernel<<<(64 * 1664 + 255) / 256, 256, 0, stream>>>(fcW, wfc);
  xpad_kernel<<<(TT * BT * 64) / 256, 256, 0, stream>>>(primary, evo, emb, xpad);
  small_init_kernel<<<209, 256, 0, stream>>>(zb, flags0, sinA, cosA, alpha);

  L0Args a0;
  a0.xpad = xpad; a0.wx0 = wx0; a0.zero = zb;
  a0.Whh0f = Whh0f; a0.Whh0b = Whh0b; a0.b0f = b0f; a0.b0b = b0b;
  a0.h0 = h0; a0.flags = flags0;
  lstm_l0<<<NWG, 256, LDS_L0, stream>>>(a0);

  for (int k = 0; k < TT / CH; ++k) {
    GMArgs g;
    g.h0 = h0; g.Wih1f = Wih1f; g.Wih1b = Wih1b; g.b1f = b1f; g.b1b = b1b;
    g.xg = xg1; g.k0 = k * CH;
    gemm_xg1<<<dim3(100, 2), 256, LDS_GM, stream>>>(g);

    L1Args a1;
    a1.xg = xg1; a1.zero = zb;
    a1.Whh1f = Whh1f; a1.Whh1b = Whh1b;
    a1.h1 = h1; a1.cst = cst; a1.flags = flags1; a1.s0 = k * CH;
    lstm_l1<<<NWG, 256, LDS_L1, stream>>>(a1);
  }

  fc_kernel<<<TT, 256, 0, stream>>>(h1, xpad, wfc, fcb, sinA, cosA, pts);
  nerf_kernel<<<1, 64, 0, stream>>>(pts, (float*)d_out);
}

// Round 10
// 11474.915 us; speedup vs baseline: 1.9584x; 1.0010x over previous
//
#include <hip/hip_runtime.h>
#include <hip/hip_bf16.h>
#include <math.h>

// ---------------------------------------------------------------------------
// RGN model: T=700 B=32 H=800 EMB=32 EVO=21 A=60
// f32 in / f32 out; internal bf16 MFMA.
// L0: persistent recurrence, Whh0 LDS-resident.
// L1: per chunk, each WG computes the xg rows it owns (Wih1 B-frags cached
//     in registers, h0[t] staged to LDS in 2 passes), then runs the
//     recurrence (Whh1 LDS-resident). No separate GEMM kernel.
// ---------------------------------------------------------------------------

typedef unsigned int u32;
typedef __bf16 bf16x8 __attribute__((ext_vector_type(8)));
typedef __bf16 bf16x4 __attribute__((ext_vector_type(4)));
typedef float  f32x4  __attribute__((ext_vector_type(4)));

#define TT 700
#define BT 32
#define HROW 1664          // 800 fwd | 32 pad | 800 bwd | 32 pad
#define NWG 100
#define CH 50              // L1 chunk length (14 chunks)
#define LDS_L0 (108 * 512 + 102400)   // 157,696 B
#define LDS_L1 (100 * 512 + 102400)   // 153,600 B

__device__ __forceinline__ f32x4 mfma16(bf16x8 a, bf16x8 b, f32x4 c) {
  return __builtin_amdgcn_mfma_f32_16x16x32_bf16(a, b, c, 0, 0, 0);
}
__device__ __forceinline__ float sigf(float x) { return 1.f / (1.f + __expf(-x)); }

#define ALOAD(p)    __hip_atomic_load((p), __ATOMIC_RELAXED, __HIP_MEMORY_SCOPE_AGENT)
#define ASTORE(p,v) __hip_atomic_store((p), (v), __ATOMIC_RELAXED, __HIP_MEMORY_SCOPE_AGENT)

__device__ __forceinline__ bf16x8 cvt8(f32x4 a, f32x4 b) {
  bf16x8 r;
  r[0] = (__bf16)a[0]; r[1] = (__bf16)a[1]; r[2] = (__bf16)a[2]; r[3] = (__bf16)a[3];
  r[4] = (__bf16)b[0]; r[5] = (__bf16)b[1]; r[6] = (__bf16)b[2]; r[7] = (__bf16)b[3];
  return r;
}

// ---------------- pack / init kernels ----------------
__global__ void pack_wx0_kernel(const float* Wih0f, const float* Wih0b, __bf16* wx0) {
  int idx = blockIdx.x * 256 + threadIdx.x;      // 2*3200*64 exact
  if (idx >= 2 * 3200 * 64) return;
  int d = idx / (3200 * 64);
  int r = (idx / 64) % 3200;
  int k = idx % 64;
  const float* W = d ? Wih0b : Wih0f;
  wx0[idx] = (k < 53) ? (__bf16)W[(size_t)r * 53 + k] : (__bf16)0.f;
}

__global__ void pack_fc_kernel(const float* fcW, __bf16* wfc) {
  int idx = blockIdx.x * 256 + threadIdx.x;
  if (idx >= 64 * 1664) return;
  int a = idx / 1664, k = idx % 1664;
  __bf16 v = (__bf16)0.f;
  if (a < 60 && k < 1653) v = (__bf16)fcW[(size_t)a * 1653 + k];
  wfc[idx] = v;
}

__global__ void xpad_kernel(const int* primary, const float* evo,
                            const float* emb, __bf16* xpad) {
  int idx = blockIdx.x * 256 + threadIdx.x;   // 700*32*64 exact
  int t = idx >> 11;
  int b = (idx >> 6) & 31;
  int k = idx & 63;
  __bf16 v = (__bf16)0.f;
  if (k < 32)      v = (__bf16)emb[primary[t * 32 + b] * 32 + k];
  else if (k < 53) v = (__bf16)evo[((size_t)t * 32 + b) * 21 + (k - 32)];
  xpad[idx] = v;
}

__global__ void small_init_kernel(__bf16* zerobuf, u32* flags,
                                  float* sinA, float* cosA, const float* alpha) {
  int idx = blockIdx.x * 256 + threadIdx.x;
  if (idx < 32 * HROW) zerobuf[idx] = (__bf16)0.f;
  if (idx < 6400) flags[idx] = 0u;
  int j = idx - 32 * HROW;
  if (j >= 0 && j < 192) {
    if (j < 180) {
      float v = alpha[j];
      sinA[j] = sinf(v);
      cosA[j] = cosf(v);
    } else { sinA[j] = 0.f; cosA[j] = 0.f; }
  }
}

// ---------------- barrier ----------------
__device__ __forceinline__ void rec_barrier(u32* flags, unsigned gen,
                                            int base, int count) {
  asm volatile("s_waitcnt vmcnt(0)" ::: "memory");
  __syncthreads();
  const int tid = threadIdx.x;
  if (tid == 0) ASTORE(flags + (size_t)blockIdx.x * 32, gen);
  if (tid < 64) {
    int spin = 0;
    for (;;) {
      bool ok = true;
      for (int j = tid; j < count; j += 64)
        ok = ok && (ALOAD(flags + (size_t)(base + j) * 32) >= gen);
      if (__popcll(__ballot(ok)) == 64) break;
      if (++spin > 24) __builtin_amdgcn_s_sleep(1);
    }
  }
  __syncthreads();
}

// ---------------- L0 persistent recurrence ----------------
struct L0Args {
  const __bf16 *xpad, *wx0, *zero;
  const float *Whh0f, *Whh0b, *b0f, *b0b;
  __bf16* h0;
  u32* flags;
};

__global__ __launch_bounds__(256, 1) void lstm_l0(L0Args A) {
  extern __shared__ __bf16 u2[];
  const int wg = blockIdx.x, d = wg / 50, u0 = (wg % 50) * 16;
  const int tid = threadIdx.x, w = tid >> 6, l = tid & 63;
  const int nidx = l & 15, q = l >> 4, bL = l & 31, gl = l >> 5;
  const int dcol = d * 832;
  const int row = w * 800 + u0 + nidx;
  const float bias_n = (d ? A.b0b : A.b0f)[row];
  const float* wrf = (d ? A.Whh0b : A.Whh0f) + (size_t)row * 800 + q * 8;
  __bf16* wlds = u2 + 108 * 256;
  float* g_lds = (float*)u2;
  const int bb = tid >> 3, up = tid & 7;

#pragma unroll
  for (int sl = 0; sl < 25; ++sl) {
    f32x4 wa = *(const f32x4*)(wrf + sl * 32);
    f32x4 wb = *(const f32x4*)(wrf + sl * 32 + 4);
    *(bf16x8*)(wlds + ((size_t)(w * 25 + sl) * 64 + l) * 8) = cvt8(wa, wb);
  }
  const __bf16* wx_row = A.wx0 + (size_t)d * 3200 * 64 + (size_t)row * 64 + q * 8;
  bf16x8 wx_r0 = *(const bf16x8*)wx_row;
  bf16x8 wx_r1 = *(const bf16x8*)(wx_row + 32);
  __syncthreads();

  float cA = 0.f, cB = 0.f;
#pragma unroll 1
  for (int s = 0; s < TT; ++s) {
    const int tt = d ? (TT - 1 - s) : s;
    const __bf16* hprev =
        (s == 0) ? A.zero : (A.h0 + (size_t)(d ? tt + 1 : tt - 1) * (BT * HROW));

    bf16x8 hreg[13];
    const __bf16* hsrc = hprev + (size_t)bL * HROW + dcol;
#pragma unroll
    for (int i = 0; i < 12; ++i)
      hreg[i] = *(const bf16x8*)(hsrc + (i * 8 + w * 2 + gl) * 8);
    if (w < 2) hreg[12] = *(const bf16x8*)(hsrc + (96 + w * 2 + gl) * 8);
    bf16x8 xv = *(const bf16x8*)(A.xpad + ((size_t)tt * BT + bL) * 64 + (tid >> 5) * 8);

#pragma unroll
    for (int i = 0; i < 12; ++i)
      *(bf16x8*)(u2 + (size_t)(i * 8 + w * 2 + gl) * 256 + bL * 8) = hreg[i];
    if (w < 2)
      *(bf16x8*)(u2 + (size_t)(96 + w * 2 + gl) * 256 + bL * 8) = hreg[12];
    *(bf16x8*)(u2 + (size_t)(100 + (tid >> 5)) * 256 + bL * 8) = xv;
    __syncthreads();

    f32x4 acc0 = {0.f, 0.f, 0.f, 0.f}, acc1 = {0.f, 0.f, 0.f, 0.f};
#pragma unroll
    for (int sl = 0; sl < 27; ++sl) {
      bf16x8 bfr;
      if (sl < 25)
        bfr = *(const bf16x8*)(wlds + ((size_t)(w * 25 + sl) * 64 + l) * 8);
      else
        bfr = (sl == 25) ? wx_r0 : wx_r1;
      const __bf16* ab = u2 + (size_t)(sl * 4 + q) * 256 + nidx * 8;
      bf16x8 a0 = *(const bf16x8*)ab;
      bf16x8 a1 = *(const bf16x8*)(ab + 128);
      acc0 = mfma16(a0, bfr, acc0);
      acc1 = mfma16(a1, bfr, acc1);
    }
    __syncthreads();

#pragma unroll
    for (int r = 0; r < 4; ++r) {
      g_lds[w * 512 + (q * 4 + r) * 16 + nidx]      = acc0[r] + bias_n;
      g_lds[w * 512 + (16 + q * 4 + r) * 16 + nidx] = acc1[r] + bias_n;
    }
    __syncthreads();

    {
      const int uA = 2 * up, uB = uA + 1;
      float iA = g_lds[0 * 512 + bb * 16 + uA], fA = g_lds[1 * 512 + bb * 16 + uA];
      float gA = g_lds[2 * 512 + bb * 16 + uA], oA = g_lds[3 * 512 + bb * 16 + uA];
      cA = sigf(fA) * cA + sigf(iA) * tanhf(gA);
      float hA = sigf(oA) * tanhf(cA);
      float iB = g_lds[0 * 512 + bb * 16 + uB], fB = g_lds[1 * 512 + bb * 16 + uB];
      float gB = g_lds[2 * 512 + bb * 16 + uB], oB = g_lds[3 * 512 + bb * 16 + uB];
      cB = sigf(fB) * cB + sigf(iB) * tanhf(gB);
      float hB = sigf(oB) * tanhf(cB);
      union { u32 u; __bf16 h2[2]; } pk;
      pk.h2[0] = (__bf16)hA;
      pk.h2[1] = (__bf16)hB;
      ASTORE((u32*)(A.h0 + ((size_t)tt * BT + bb) * HROW + dcol + u0 + uA), pk.u);
    }

    if (s < TT - 1) rec_barrier(A.flags, (unsigned)(s + 1), d * 50, 50);
  }
}

// ---------------- L1: fused xg GEMM + persistent recurrence (one chunk) ----
struct L1Args {
  const __bf16 *h0, *zero;
  const float *Whh1f, *Whh1b, *Wih1f, *Wih1b, *b1f, *b1b;
  __bf16 *h1, *xg;
  float* cst;
  u32* flags;
  int s0;
};

__global__ __launch_bounds__(256, 1) void lstm_l1(L1Args A) {
  extern __shared__ __bf16 u2[];
  const int wg = blockIdx.x, d = wg / 50, u0 = (wg % 50) * 16;
  const int tid = threadIdx.x, w = tid >> 6, l = tid & 63;
  const int nidx = l & 15, q = l >> 4, bL = l & 31, gl = l >> 5;
  const int dcol = d * 832;
  const int row = w * 800 + u0 + nidx;
  __bf16* wlds = u2 + 100 * 256;
  float* g_lds = (float*)u2;
  const int bb = tid >> 3, up = tid & 7;
  const float bn = (d ? A.b1b : A.b1f)[row];

  // ---- Phase A: cache this WG's Wih1 rows as 50 B-frags in registers ----
  bf16x8 breg[50];
  {
    const float* wi = (d ? A.Wih1b : A.Wih1f) + (size_t)row * 1600 + q * 8;
#pragma unroll
    for (int sl = 0; sl < 50; ++sl) {
      f32x4 wa = *(const f32x4*)(wi + sl * 32);
      f32x4 wb = *(const f32x4*)(wi + sl * 32 + 4);
      breg[sl] = cvt8(wa, wb);
    }
  }

  // ---- Phase B: xg = Wih1*h0 + b1 for this chunk (t inner, LDS-staged A) ----
#pragma unroll 1
  for (int tloc = 0; tloc < CH; ++tloc) {
    const int t = d ? (TT - 1 - A.s0 - tloc) : (A.s0 + tloc);
    f32x4 acc0 = {0.f, 0.f, 0.f, 0.f}, acc1 = {0.f, 0.f, 0.f, 0.f};
#pragma unroll
    for (int pass = 0; pass < 2; ++pass) {
      const __bf16* hsrc = A.h0 + ((size_t)t * BT + bL) * HROW + pass * 832;
      bf16x8 hreg[13];
#pragma unroll
      for (int i = 0; i < 12; ++i)
        hreg[i] = *(const bf16x8*)(hsrc + (i * 8 + w * 2 + gl) * 8);
      if (w < 2) hreg[12] = *(const bf16x8*)(hsrc + (96 + w * 2 + gl) * 8);
#pragma unroll
      for (int i = 0; i < 12; ++i)
        *(bf16x8*)(u2 + (size_t)(i * 8 + w * 2 + gl) * 256 + bL * 8) = hreg[i];
      if (w < 2)
        *(bf16x8*)(u2 + (size_t)(96 + w * 2 + gl) * 256 + bL * 8) = hreg[12];
      __syncthreads();
#pragma unroll
      for (int sl = 0; sl < 25; ++sl) {
        const __bf16* ab = u2 + (size_t)(sl * 4 + q) * 256 + nidx * 8;
        bf16x8 a0 = *(const bf16x8*)ab;
        bf16x8 a1 = *(const bf16x8*)(ab + 128);
        acc0 = mfma16(a0, breg[pass * 25 + sl], acc0);
        acc1 = mfma16(a1, breg[pass * 25 + sl], acc1);
      }
      __syncthreads();
    }
    __bf16* op = A.xg + ((size_t)(d * CH + tloc) * 3200 + row) * 32 + q * 4;
    bf16x4 v0, v1;
#pragma unroll
    for (int r = 0; r < 4; ++r) {
      v0[r] = (__bf16)(acc0[r] + bn);
      v1[r] = (__bf16)(acc1[r] + bn);
    }
    *(bf16x4*)op = v0;
    *(bf16x4*)(op + 16) = v1;
  }

  // ---- preload Whh1 into LDS ----
  {
    const float* wrf = (d ? A.Whh1b : A.Whh1f) + (size_t)row * 800 + q * 8;
#pragma unroll
    for (int sl = 0; sl < 25; ++sl) {
      f32x4 wa = *(const f32x4*)(wrf + sl * 32);
      f32x4 wb = *(const f32x4*)(wrf + sl * 32 + 4);
      *(bf16x8*)(wlds + ((size_t)(w * 25 + sl) * 64 + l) * 8) = cvt8(wa, wb);
    }
  }
  float cA = 0.f, cB = 0.f;
  float* cp = A.cst + ((size_t)d * 32 + bb) * 800 + u0 + 2 * up;
  if (A.s0 > 0) { cA = cp[0]; cB = cp[1]; }
  __syncthreads();

  // ---- Phase C: recurrence ----
#pragma unroll 1
  for (int si = 0; si < CH; ++si) {
    const int s = A.s0 + si;
    const int tt = d ? (TT - 1 - s) : s;
    const __bf16* hprev =
        (s == 0) ? A.zero : (A.h1 + (size_t)(d ? tt + 1 : tt - 1) * (BT * HROW));

    const __bf16* xgp = A.xg + ((size_t)(d * CH + si) * 3200 + row) * 32 + q * 4;
    bf16x4 xa = *(const bf16x4*)xgp;
    bf16x4 xb = *(const bf16x4*)(xgp + 16);
    f32x4 acc0 = {(float)xa[0], (float)xa[1], (float)xa[2], (float)xa[3]};
    f32x4 acc1 = {(float)xb[0], (float)xb[1], (float)xb[2], (float)xb[3]};

    bf16x8 hreg[13];
    const __bf16* hsrc = hprev + (size_t)bL * HROW + dcol;
#pragma unroll
    for (int i = 0; i < 12; ++i)
      hreg[i] = *(const bf16x8*)(hsrc + (i * 8 + w * 2 + gl) * 8);
    if (w < 2) hreg[12] = *(const bf16x8*)(hsrc + (96 + w * 2 + gl) * 8);

#pragma unroll
    for (int i = 0; i < 12; ++i)
      *(bf16x8*)(u2 + (size_t)(i * 8 + w * 2 + gl) * 256 + bL * 8) = hreg[i];
    if (w < 2)
      *(bf16x8*)(u2 + (size_t)(96 + w * 2 + gl) * 256 + bL * 8) = hreg[12];
    __syncthreads();

#pragma unroll
    for (int sl = 0; sl < 25; ++sl) {
      bf16x8 bfr = *(const bf16x8*)(wlds + ((size_t)(w * 25 + sl) * 64 + l) * 8);
      const __bf16* ab = u2 + (size_t)(sl * 4 + q) * 256 + nidx * 8;
      bf16x8 a0 = *(const bf16x8*)ab;
      bf16x8 a1 = *(const bf16x8*)(ab + 128);
      acc0 = mfma16(a0, bfr, acc0);
      acc1 = mfma16(a1, bfr, acc1);
    }
    __syncthreads();

#pragma unroll
    for (int r = 0; r < 4; ++r) {
      g_lds[w * 512 + (q * 4 + r) * 16 + nidx]      = acc0[r];
      g_lds[w * 512 + (16 + q * 4 + r) * 16 + nidx] = acc1[r];
    }
    __syncthreads();

    {
      const int uA = 2 * up, uB = uA + 1;
      float iA = g_lds[0 * 512 + bb * 16 + uA], fA = g_lds[1 * 512 + bb * 16 + uA];
      float gA = g_lds[2 * 512 + bb * 16 + uA], oA = g_lds[3 * 512 + bb * 16 + uA];
      cA = sigf(fA) * cA + sigf(iA) * tanhf(gA);
      float hA = sigf(oA) * tanhf(cA);
      float iB = g_lds[0 * 512 + bb * 16 + uB], fB = g_lds[1 * 512 + bb * 16 + uB];
      float gB = g_lds[2 * 512 + bb * 16 + uB], oB = g_lds[3 * 512 + bb * 16 + uB];
      cB = sigf(fB) * cB + sigf(iB) * tanhf(gB);
      float hB = sigf(oB) * tanhf(cB);
      union { u32 u; __bf16 h2[2]; } pk;
      pk.h2[0] = (__bf16)hA;
      pk.h2[1] = (__bf16)hB;
      ASTORE((u32*)(A.h1 + ((size_t)tt * BT + bb) * HROW + dcol + u0 + uA), pk.u);
    }

    if (si < CH - 1) rec_barrier(A.flags, (unsigned)(s + 1), d * 50, 50);
  }
  if (A.s0 + CH < TT) { cp[0] = cA; cp[1] = cB; }
}

// ---------------- FC + softmax + dihedral -> points ----------------
__global__ __launch_bounds__(256) void fc_kernel(
    const __bf16* __restrict__ h1, const __bf16* __restrict__ xpad,
    const __bf16* __restrict__ wfc, const float* __restrict__ fcb,
    const float* __restrict__ sinA, const float* __restrict__ cosA,
    float* __restrict__ pts) {
  __shared__ float lg[32 * 64];
  const int t = blockIdx.x, tid = threadIdx.x;
  const int wave = tid >> 6, lane = tid & 63, nidx = lane & 15, q = lane >> 4;
  const int a_col = wave * 16 + nidx;
  const __bf16* wrow = wfc + (size_t)a_col * 1664 + q * 8;
  const __bf16* h1row = h1 + (size_t)t * BT * HROW;
  const __bf16* xrow  = xpad + (size_t)t * BT * 64;
  f32x4 acc0 = {0.f, 0.f, 0.f, 0.f}, acc1 = {0.f, 0.f, 0.f, 0.f};
#pragma unroll
  for (int sl = 0; sl < 52; ++sl) {
    const int k = sl * 32 + q * 8;
    bf16x8 a0, a1;
    if (sl < 50) {
      const int kp = (sl < 25) ? k : (k + 32);
      a0 = *(const bf16x8*)(h1row + (size_t)nidx * HROW + kp);
      a1 = *(const bf16x8*)(h1row + (size_t)(16 + nidx) * HROW + kp);
    } else {
      a0 = *(const bf16x8*)(xrow + nidx * 64 + (k - 1600));
      a1 = *(const bf16x8*)(xrow + (16 + nidx) * 64 + (k - 1600));
    }
    bf16x8 bfr = *(const bf16x8*)(wrow + sl * 32);
    acc0 = mfma16(a0, bfr, acc0);
    acc1 = mfma16(a1, bfr, acc1);
  }
  const float bn = (a_col < 60) ? fcb[a_col] : -1e30f;
#pragma unroll
  for (int r = 0; r < 4; ++r) {
    lg[(q * 4 + r) * 64 + a_col]      = acc0[r] + bn;
    lg[(16 + q * 4 + r) * 64 + a_col] = acc1[r] + bn;
  }
  __syncthreads();

  const int b = tid >> 3, j = tid & 7;
  float v[8];
  float m = -1e30f;
#pragma unroll
  for (int k2 = 0; k2 < 8; ++k2) {
    v[k2] = lg[b * 64 + j + 8 * k2];
    m = fmaxf(m, v[k2]);
  }
  m = fmaxf(m, __shfl_xor(m, 1, 8));
  m = fmaxf(m, __shfl_xor(m, 2, 8));
  m = fmaxf(m, __shfl_xor(m, 4, 8));
  float s = 0.f;
#pragma unroll
  for (int k2 = 0; k2 < 8; ++k2) { v[k2] = __expf(v[k2] - m); s += v[k2]; }
  s += __shfl_xor(s, 1, 8);
  s += __shfl_xor(s, 2, 8);
  s += __shfl_xor(s, 4, 8);
  const float inv = 1.f / s;
  float ps[3] = {0.f, 0.f, 0.f}, pc[3] = {0.f, 0.f, 0.f};
#pragma unroll
  for (int k2 = 0; k2 < 8; ++k2) {
    const int a = j + 8 * k2;
    const float p = v[k2] * inv;
#pragma unroll
    for (int c = 0; c < 3; ++c) {
      ps[c] += p * sinA[a * 3 + c];
      pc[c] += p * cosA[a * 3 + c];
    }
  }
#pragma unroll
  for (int c = 0; c < 3; ++c) {
    ps[c] += __shfl_xor(ps[c], 1, 8);
    ps[c] += __shfl_xor(ps[c], 2, 8);
    ps[c] += __shfl_xor(ps[c], 4, 8);
    pc[c] += __shfl_xor(pc[c], 1, 8);
    pc[c] += __shfl_xor(pc[c], 2, 8);
    pc[c] += __shfl_xor(pc[c], 4, 8);
  }
  if (j == 0) {
    const float BL[3] = {145.801f, 152.326f, 132.868f};
    const float BA[3] = {2.124f, 1.941f, 2.028f};
#pragma unroll
    for (int c = 0; c < 3; ++c) {
      const float ang = 3.14159265358979323846f - BA[c];
      const float rct = BL[c] * cosf(ang), rst = BL[c] * sinf(ang);
      const float dih = atan2f(ps[c], pc[c]);
      float* o = pts + ((size_t)(3 * t + c) * BT + b) * 3;
      o[0] = rct;
      o[1] = cosf(dih) * rst;
      o[2] = sinf(dih) * rst;
    }
  }
}

// ---------------- sequential NeRF extension ----------------
__global__ void nerf_kernel(const float* __restrict__ pts, float* __restrict__ out) {
  const int b = threadIdx.x;
  if (b >= 32) return;
  float ax = -0.70710678f, ay = 1.22474487f, az = 0.f;
  float bx = -1.41421356f, by = 0.f, bz = 0.f;
  float cx = 0.f, cy = 0.f, cz = 0.f;
#pragma unroll 4
  for (int i = 0; i < 3 * TT; ++i) {
    const float* p = pts + ((size_t)i * BT + b) * 3;
    const float p0 = p[0], p1 = p[1], p2 = p[2];
    float ux = cx - bx, uy = cy - by, uz = cz - bz;
    const float ri = rsqrtf(ux * ux + uy * uy + uz * uz + 1e-12f);
    ux *= ri; uy *= ri; uz *= ri;
    const float wx = bx - ax, wy = by - ay, wz = bz - az;
    float nx = wy * uz - wz * uy, ny = wz * ux - wx * uz, nz = wx * uy - wy * ux;
    const float rn = rsqrtf(nx * nx + ny * ny + nz * nz + 1e-12f);
    nx *= rn; ny *= rn; nz *= rn;
    const float mx = ny * uz - nz * uy, my = nz * ux - nx * uz, mz = nx * uy - ny * ux;
    const float ox = cx + p0 * ux + p1 * mx + p2 * nx;
    const float oy = cy + p0 * uy + p1 * my + p2 * ny;
    const float oz = cz + p0 * uz + p1 * mz + p2 * nz;
    out[((size_t)i * BT + b) * 3 + 0] = ox;
    out[((size_t)i * BT + b) * 3 + 1] = oy;
    out[((size_t)i * BT + b) * 3 + 2] = oz;
    ax = bx; ay = by; az = bz;
    bx = cx; by = cy; bz = cz;
    cx = ox; cy = oy; cz = oz;
  }
}

// ---------------- launch ----------------
extern "C" void kernel_launch(void* const* d_in, const int* in_sizes, int n_in,
                              void* d_out, int out_size, void* d_ws, size_t ws_size,
                              hipStream_t stream) {
  (void)in_sizes; (void)n_in; (void)out_size;
  const int*   primary = (const int*)d_in[0];
  const float* evo     = (const float*)d_in[1];
  const float* emb     = (const float*)d_in[3];
  const float* Wih0f   = (const float*)d_in[4];
  const float* Whh0f   = (const float*)d_in[5];
  const float* b0f     = (const float*)d_in[6];
  const float* Wih0b   = (const float*)d_in[7];
  const float* Whh0b   = (const float*)d_in[8];
  const float* b0b     = (const float*)d_in[9];
  const float* Wih1f   = (const float*)d_in[10];
  const float* Whh1f   = (const float*)d_in[11];
  const float* b1f     = (const float*)d_in[12];
  const float* Wih1b   = (const float*)d_in[13];
  const float* Whh1b   = (const float*)d_in[14];
  const float* b1b     = (const float*)d_in[15];
  const float* fcW     = (const float*)d_in[16];
  const float* fcb     = (const float*)d_in[17];
  const float* alpha   = (const float*)d_in[18];

  char* ws = (char*)d_ws;
  size_t off = 0;
  auto take = [&](size_t n) -> void* {
    void* p = ws + off;
    off += (n + 511) & ~(size_t)511;
    return p;
  };
  __bf16* xpad = (__bf16*)take((size_t)TT * BT * 64 * 2);
  __bf16* zb   = (__bf16*)take((size_t)BT * HROW * 2);
  __bf16* wx0  = (__bf16*)take((size_t)2 * 3200 * 64 * 2);
  __bf16* wfc  = (__bf16*)take((size_t)64 * 1664 * 2);
  float*  sinA = (float*)take(192 * 4);
  float*  cosA = (float*)take(192 * 4);
  float*  pts  = (float*)take((size_t)3 * TT * BT * 3 * 4);
  u32*    flags0 = (u32*)take(6400 * 4);
  u32*    flags1 = flags0 + 3200;
  float*  cst  = (float*)take((size_t)2 * 32 * 800 * 4);
  __bf16* xg1  = (__bf16*)take((size_t)2 * CH * 3200 * 32 * 2);
  __bf16* h0   = (__bf16*)take((size_t)TT * BT * HROW * 2);
  __bf16* h1   = (__bf16*)take((size_t)TT * BT * HROW * 2);
  if (off > ws_size) return;  // failure signature: absmax == max|ref| == 233472

  static int lds_cfg = 0;
  if (!lds_cfg) {
    hipFuncSetAttribute((const void*)lstm_l0,
                        hipFuncAttributeMaxDynamicSharedMemorySize, LDS_L0);
    hipFuncSetAttribute((const void*)lstm_l1,
                        hipFuncAttributeMaxDynamicSharedMemorySize, LDS_L1);
    lds_cfg = 1;
  }

  pack_wx0_kernel<<<1600, 256, 0, stream>>>(Wih0f, Wih0b, wx0);
  pack_fc_kernel<<<(64 * 1664 + 255) / 256, 256, 0, stream>>>(fcW, wfc);
  xpad_kernel<<<(TT * BT * 64) / 256, 256, 0, stream>>>(primary, evo, emb, xpad);
  small_init_kernel<<<209, 256, 0, stream>>>(zb, flags0, sinA, cosA, alpha);

  L0Args a0;
  a0.xpad = xpad; a0.wx0 = wx0; a0.zero = zb;
  a0.Whh0f = Whh0f; a0.Whh0b = Whh0b; a0.b0f = b0f; a0.b0b = b0b;
  a0.h0 = h0; a0.flags = flags0;
  lstm_l0<<<NWG, 256, LDS_L0, stream>>>(a0);

  for (int k = 0; k < TT / CH; ++k) {
    L1Args a1;
    a1.h0 = h0; a1.zero = zb;
    a1.Whh1f = Whh1f; a1.Whh1b = Whh1b;
    a1.Wih1f = Wih1f; a1.Wih1b = Wih1b;
    a1.b1f = b1f; a1.b1b = b1b;
    a1.h1 = h1; a1.xg = xg1; a1.cst = cst; a1.flags = flags1; a1.s0 = k * CH;
    lstm_l1<<<NWG, 256, LDS_L1, stream>>>(a1);
  }

  fc_kernel<<<TT, 256, 0, stream>>>(h1, xpad, wfc, fcb, sinA, cosA, pts);
  nerf_kernel<<<1, 64, 0, stream>>>(pts, (float*)d_out);
}

// Round 11
// 11157.458 us; speedup vs baseline: 2.0142x; 1.0285x over previous
//
#include <hip/hip_runtime.h>
#include <hip/hip_bf16.h>
#include <math.h>

// ---------------------------------------------------------------------------
// RGN model: T=700 B=32 H=800 EMB=32 EVO=21 A=60
// f32 in / f32 out; internal bf16 MFMA.
// L0: persistent recurrence, Whh0 LDS-resident (100 WGs).
// L1: ONE persistent kernel, 256 WGs: 100 recurrence WGs (Whh1 LDS-resident,
//     c in registers) + 156 gemm WGs producing xg = Wih1*h0 + b1 one chunk
//     ahead into a 2-slot ring (flag handshake; rec reads xg via L2-bypass
//     atomics since slots are reused).
// ---------------------------------------------------------------------------

typedef unsigned int u32;
typedef unsigned long long u64;
typedef __bf16 bf16x8 __attribute__((ext_vector_type(8)));
typedef float  f32x4  __attribute__((ext_vector_type(4)));

#define TT 700
#define BT 32
#define HROW 1664          // 800 fwd | 32 pad | 800 bwd | 32 pad
#define CH 50              // chunk length (14 chunks)
#define NCH (TT / CH)
#define SLOT ((size_t)2 * CH * 3200 * 32)      // bf16 elems per xg slot
#define LDS_L0 (108 * 512 + 102400)   // 157,696 B
#define LDS_L1 (100 * 512 + 102400)   // 153,600 B

__device__ __forceinline__ f32x4 mfma16(bf16x8 a, bf16x8 b, f32x4 c) {
  return __builtin_amdgcn_mfma_f32_16x16x32_bf16(a, b, c, 0, 0, 0);
}
__device__ __forceinline__ float sigf(float x) { return 1.f / (1.f + __expf(-x)); }

#define ALOAD(p)    __hip_atomic_load((p), __ATOMIC_RELAXED, __HIP_MEMORY_SCOPE_AGENT)
#define ASTORE(p,v) __hip_atomic_store((p), (v), __ATOMIC_RELAXED, __HIP_MEMORY_SCOPE_AGENT)

__device__ __forceinline__ bf16x8 cvt8(f32x4 a, f32x4 b) {
  bf16x8 r;
  r[0] = (__bf16)a[0]; r[1] = (__bf16)a[1]; r[2] = (__bf16)a[2]; r[3] = (__bf16)a[3];
  r[4] = (__bf16)b[0]; r[5] = (__bf16)b[1]; r[6] = (__bf16)b[2]; r[7] = (__bf16)b[3];
  return r;
}

// ---------------- pack / init kernels ----------------
__global__ void pack_wx0_kernel(const float* Wih0f, const float* Wih0b, __bf16* wx0) {
  int idx = blockIdx.x * 256 + threadIdx.x;      // 2*3200*64 exact
  if (idx >= 2 * 3200 * 64) return;
  int d = idx / (3200 * 64);
  int r = (idx / 64) % 3200;
  int k = idx % 64;
  const float* W = d ? Wih0b : Wih0f;
  wx0[idx] = (k < 53) ? (__bf16)W[(size_t)r * 53 + k] : (__bf16)0.f;
}

__global__ void pack_fc_kernel(const float* fcW, __bf16* wfc) {
  int idx = blockIdx.x * 256 + threadIdx.x;
  if (idx >= 64 * 1664) return;
  int a = idx / 1664, k = idx % 1664;
  __bf16 v = (__bf16)0.f;
  if (a < 60 && k < 1653) v = (__bf16)fcW[(size_t)a * 1653 + k];
  wfc[idx] = v;
}

__global__ void xpad_kernel(const int* primary, const float* evo,
                            const float* emb, __bf16* xpad) {
  int idx = blockIdx.x * 256 + threadIdx.x;   // 700*32*64 exact
  int t = idx >> 11;
  int b = (idx >> 6) & 31;
  int k = idx & 63;
  __bf16 v = (__bf16)0.f;
  if (k < 32)      v = (__bf16)emb[primary[t * 32 + b] * 32 + k];
  else if (k < 53) v = (__bf16)evo[((size_t)t * 32 + b) * 21 + (k - 32)];
  xpad[idx] = v;
}

__global__ void small_init_kernel(__bf16* zerobuf, u32* flags,
                                  float* sinA, float* cosA, const float* alpha) {
  int idx = blockIdx.x * 256 + threadIdx.x;
  if (idx < 32 * HROW) zerobuf[idx] = (__bf16)0.f;
  if (idx < 11392) flags[idx] = 0u;   // l0: 100 lines; l1: 256 lines (x32 u32)
  int j = idx - 32 * HROW;
  if (j >= 0 && j < 192) {
    if (j < 180) {
      float v = alpha[j];
      sinA[j] = sinf(v);
      cosA[j] = cosf(v);
    } else { sinA[j] = 0.f; cosA[j] = 0.f; }
  }
}

// ---------------- flag helpers ----------------
__device__ __forceinline__ void wait_lines(u32* flags, int base, int count,
                                           unsigned gen) {
  const int tid = threadIdx.x;
  if (tid < 64) {
    int spin = 0;
    for (;;) {
      bool ok = true;
      for (int j = tid; j < count; j += 64)
        ok = ok && (ALOAD(flags + (size_t)(base + j) * 32) >= gen);
      if (__popcll(__ballot(ok)) == 64) break;
      if (++spin > 24) __builtin_amdgcn_s_sleep(1);
    }
  }
  __syncthreads();
}

__device__ __forceinline__ void rec_barrier(u32* flags, unsigned gen,
                                            int base, int count) {
  asm volatile("s_waitcnt vmcnt(0)" ::: "memory");
  __syncthreads();
  if (threadIdx.x == 0) ASTORE(flags + (size_t)blockIdx.x * 32, gen);
  wait_lines(flags, base, count, gen);
}

// ---------------- L0 persistent recurrence ----------------
struct L0Args {
  const __bf16 *xpad, *wx0, *zero;
  const float *Whh0f, *Whh0b, *b0f, *b0b;
  __bf16* h0;
  u32* flags;
};

__global__ __launch_bounds__(256, 1) void lstm_l0(L0Args A) {
  extern __shared__ __bf16 u2[];
  const int wg = blockIdx.x, d = wg / 50, u0 = (wg % 50) * 16;
  const int tid = threadIdx.x, w = tid >> 6, l = tid & 63;
  const int nidx = l & 15, q = l >> 4, bL = l & 31, gl = l >> 5;
  const int dcol = d * 832;
  const int row = w * 800 + u0 + nidx;
  const float bias_n = (d ? A.b0b : A.b0f)[row];
  const float* wrf = (d ? A.Whh0b : A.Whh0f) + (size_t)row * 800 + q * 8;
  __bf16* wlds = u2 + 108 * 256;
  float* g_lds = (float*)u2;
  const int bb = tid >> 3, up = tid & 7;

#pragma unroll
  for (int sl = 0; sl < 25; ++sl) {
    f32x4 wa = *(const f32x4*)(wrf + sl * 32);
    f32x4 wb = *(const f32x4*)(wrf + sl * 32 + 4);
    *(bf16x8*)(wlds + ((size_t)(w * 25 + sl) * 64 + l) * 8) = cvt8(wa, wb);
  }
  const __bf16* wx_row = A.wx0 + (size_t)d * 3200 * 64 + (size_t)row * 64 + q * 8;
  bf16x8 wx_r0 = *(const bf16x8*)wx_row;
  bf16x8 wx_r1 = *(const bf16x8*)(wx_row + 32);
  __syncthreads();

  float cA = 0.f, cB = 0.f;
#pragma unroll 1
  for (int s = 0; s < TT; ++s) {
    const int tt = d ? (TT - 1 - s) : s;
    const __bf16* hprev =
        (s == 0) ? A.zero : (A.h0 + (size_t)(d ? tt + 1 : tt - 1) * (BT * HROW));

    bf16x8 hreg[13];
    const __bf16* hsrc = hprev + (size_t)bL * HROW + dcol;
#pragma unroll
    for (int i = 0; i < 12; ++i)
      hreg[i] = *(const bf16x8*)(hsrc + (i * 8 + w * 2 + gl) * 8);
    if (w < 2) hreg[12] = *(const bf16x8*)(hsrc + (96 + w * 2 + gl) * 8);
    bf16x8 xv = *(const bf16x8*)(A.xpad + ((size_t)tt * BT + bL) * 64 + (tid >> 5) * 8);

#pragma unroll
    for (int i = 0; i < 12; ++i)
      *(bf16x8*)(u2 + (size_t)(i * 8 + w * 2 + gl) * 256 + bL * 8) = hreg[i];
    if (w < 2)
      *(bf16x8*)(u2 + (size_t)(96 + w * 2 + gl) * 256 + bL * 8) = hreg[12];
    *(bf16x8*)(u2 + (size_t)(100 + (tid >> 5)) * 256 + bL * 8) = xv;
    __syncthreads();

    f32x4 acc0 = {0.f, 0.f, 0.f, 0.f}, acc1 = {0.f, 0.f, 0.f, 0.f};
#pragma unroll
    for (int sl = 0; sl < 27; ++sl) {
      bf16x8 bfr;
      if (sl < 25)
        bfr = *(const bf16x8*)(wlds + ((size_t)(w * 25 + sl) * 64 + l) * 8);
      else
        bfr = (sl == 25) ? wx_r0 : wx_r1;
      const __bf16* ab = u2 + (size_t)(sl * 4 + q) * 256 + nidx * 8;
      bf16x8 a0 = *(const bf16x8*)ab;
      bf16x8 a1 = *(const bf16x8*)(ab + 128);
      acc0 = mfma16(a0, bfr, acc0);
      acc1 = mfma16(a1, bfr, acc1);
    }
    __syncthreads();

#pragma unroll
    for (int r = 0; r < 4; ++r) {
      g_lds[w * 512 + (q * 4 + r) * 16 + nidx]      = acc0[r] + bias_n;
      g_lds[w * 512 + (16 + q * 4 + r) * 16 + nidx] = acc1[r] + bias_n;
    }
    __syncthreads();

    {
      const int uA = 2 * up, uB = uA + 1;
      float iA = g_lds[0 * 512 + bb * 16 + uA], fA = g_lds[1 * 512 + bb * 16 + uA];
      float gA = g_lds[2 * 512 + bb * 16 + uA], oA = g_lds[3 * 512 + bb * 16 + uA];
      cA = sigf(fA) * cA + sigf(iA) * tanhf(gA);
      float hA = sigf(oA) * tanhf(cA);
      float iB = g_lds[0 * 512 + bb * 16 + uB], fB = g_lds[1 * 512 + bb * 16 + uB];
      float gB = g_lds[2 * 512 + bb * 16 + uB], oB = g_lds[3 * 512 + bb * 16 + uB];
      cB = sigf(fB) * cB + sigf(iB) * tanhf(gB);
      float hB = sigf(oB) * tanhf(cB);
      union { u32 u; __bf16 h2[2]; } pk;
      pk.h2[0] = (__bf16)hA;
      pk.h2[1] = (__bf16)hB;
      ASTORE((u32*)(A.h0 + ((size_t)tt * BT + bb) * HROW + dcol + u0 + uA), pk.u);
    }

    if (s < TT - 1) rec_barrier(A.flags, (unsigned)(s + 1), d * 50, 50);
  }
}

// ---------------- L1: persistent rec (100 WGs) + xg gemm (156 WGs) ----------
struct L1Args {
  const __bf16 *h0, *zero;
  const float *Whh1f, *Whh1b, *Wih1f, *Wih1b, *b1f, *b1b;
  __bf16 *h1, *xg;
  u32* flags;     // lines 0..99: rec; 100..255: gemm
};

__global__ __launch_bounds__(256, 1) void lstm_l1(L1Args A) {
  extern __shared__ __bf16 u2[];
  const int tid = threadIdx.x, w = tid >> 6, l = tid & 63;
  const int nidx = l & 15, q = l >> 4, bL = l & 31, gl = l >> 5;
  __bf16* wlds = u2 + 100 * 256;

  if (blockIdx.x < 100) {
    // ---------------- recurrence consumer ----------------
    const int wg = blockIdx.x, d = wg / 50, u0 = (wg % 50) * 16;
    const int dcol = d * 832;
    const int row = w * 800 + u0 + nidx;
    float* g_lds = (float*)u2;
    const int bb = tid >> 3, up = tid & 7;
    {
      const float* wrf = (d ? A.Whh1b : A.Whh1f) + (size_t)row * 800 + q * 8;
#pragma unroll
      for (int sl = 0; sl < 25; ++sl) {
        f32x4 wa = *(const f32x4*)(wrf + sl * 32);
        f32x4 wb = *(const f32x4*)(wrf + sl * 32 + 4);
        *(bf16x8*)(wlds + ((size_t)(w * 25 + sl) * 64 + l) * 8) = cvt8(wa, wb);
      }
    }
    __syncthreads();
    float cA = 0.f, cB = 0.f;

    for (int k = 0; k < NCH; ++k) {
      wait_lines(A.flags, 100, 156, (unsigned)(k + 1));   // xg chunk k ready
      const __bf16* buf = A.xg + (size_t)(k & 1) * SLOT;
#pragma unroll 1
      for (int si = 0; si < CH; ++si) {
        const int s = k * CH + si;
        const int tt = d ? (TT - 1 - s) : s;
        const __bf16* hprev =
            (s == 0) ? A.zero
                     : (A.h1 + (size_t)(d ? tt + 1 : tt - 1) * (BT * HROW));

        // xg: L2-bypassing loads (slots are reused -> cached reads unsafe)
        const u64* xga = (const u64*)(buf +
            ((size_t)(d * CH + si) * 3200 + row) * 32 + q * 4);
        u64 x0 = ALOAD(xga);
        u64 x1 = ALOAD(xga + 4);   // +32 B (batch half 2)

        bf16x8 hreg[13];
        const __bf16* hsrc = hprev + (size_t)bL * HROW + dcol;
#pragma unroll
        for (int i = 0; i < 12; ++i)
          hreg[i] = *(const bf16x8*)(hsrc + (i * 8 + w * 2 + gl) * 8);
        if (w < 2) hreg[12] = *(const bf16x8*)(hsrc + (96 + w * 2 + gl) * 8);

        union { u64 u; __bf16 h[4]; } ux0, ux1;
        ux0.u = x0; ux1.u = x1;
        f32x4 acc0 = {(float)ux0.h[0], (float)ux0.h[1],
                      (float)ux0.h[2], (float)ux0.h[3]};
        f32x4 acc1 = {(float)ux1.h[0], (float)ux1.h[1],
                      (float)ux1.h[2], (float)ux1.h[3]};

#pragma unroll
        for (int i = 0; i < 12; ++i)
          *(bf16x8*)(u2 + (size_t)(i * 8 + w * 2 + gl) * 256 + bL * 8) = hreg[i];
        if (w < 2)
          *(bf16x8*)(u2 + (size_t)(96 + w * 2 + gl) * 256 + bL * 8) = hreg[12];
        __syncthreads();

#pragma unroll
        for (int sl = 0; sl < 25; ++sl) {
          bf16x8 bfr = *(const bf16x8*)(wlds + ((size_t)(w * 25 + sl) * 64 + l) * 8);
          const __bf16* ab = u2 + (size_t)(sl * 4 + q) * 256 + nidx * 8;
          bf16x8 a0 = *(const bf16x8*)ab;
          bf16x8 a1 = *(const bf16x8*)(ab + 128);
          acc0 = mfma16(a0, bfr, acc0);
          acc1 = mfma16(a1, bfr, acc1);
        }
        __syncthreads();

#pragma unroll
        for (int r = 0; r < 4; ++r) {
          g_lds[w * 512 + (q * 4 + r) * 16 + nidx]      = acc0[r];
          g_lds[w * 512 + (16 + q * 4 + r) * 16 + nidx] = acc1[r];
        }
        __syncthreads();

        {
          const int uA = 2 * up, uB = uA + 1;
          float iA = g_lds[0 * 512 + bb * 16 + uA], fA = g_lds[1 * 512 + bb * 16 + uA];
          float gA = g_lds[2 * 512 + bb * 16 + uA], oA = g_lds[3 * 512 + bb * 16 + uA];
          cA = sigf(fA) * cA + sigf(iA) * tanhf(gA);
          float hA = sigf(oA) * tanhf(cA);
          float iB = g_lds[0 * 512 + bb * 16 + uB], fB = g_lds[1 * 512 + bb * 16 + uB];
          float gB = g_lds[2 * 512 + bb * 16 + uB], oB = g_lds[3 * 512 + bb * 16 + uB];
          cB = sigf(fB) * cB + sigf(iB) * tanhf(gB);
          float hB = sigf(oB) * tanhf(cB);
          union { u32 u; __bf16 h2[2]; } pk;
          pk.h2[0] = (__bf16)hA;
          pk.h2[1] = (__bf16)hB;
          ASTORE((u32*)(A.h1 + ((size_t)tt * BT + bb) * HROW + dcol + u0 + uA), pk.u);
        }

        if (s < TT - 1) rec_barrier(A.flags, (unsigned)(s + 1), 0 + d * 50, 50);
      }
    }
  } else {
    // ---------------- xg producer: 156 WGs, 200 tiles/chunk ----------------
    const int g = blockIdx.x - 100;
    for (int k = 0; k < NCH; ++k) {
      // slot (k&1) reused by chunk k-2's reader: wait until rec done chunk k-2
      if (k >= 2) wait_lines(A.flags, 0, 100, (unsigned)((k - 1) * CH));
      __bf16* buf = A.xg + (size_t)(k & 1) * SLOT;

      for (int tl = g; tl < 200; tl += 156) {
        const int dir = tl / 100, rt = tl % 100;
        const int rbase = rt * 32;
        const float* W = dir ? A.Wih1b : A.Wih1f;
        __syncthreads();   // protect wlds from previous tile's MFMAs
        for (int i = w * 25; i < w * 25 + 25; ++i) {
          const int rh = i / 50, sl = i % 50;
          const int rr = rbase + rh * 16 + nidx;
          const float* wp = W + (size_t)rr * 1600 + sl * 32 + q * 8;
          f32x4 wa = *(const f32x4*)wp;
          f32x4 wb = *(const f32x4*)(wp + 4);
          *(bf16x8*)(wlds + ((size_t)i * 64 + l) * 8) = cvt8(wa, wb);
        }
        __syncthreads();

        const int rh = w >> 1, bh = w & 1;
        const int rr = rbase + rh * 16 + nidx;
        const float bn = (dir ? A.b1b : A.b1f)[rr];
#pragma unroll 1
        for (int tloc = 0; tloc < CH; ++tloc) {
          const int t = dir ? (TT - 1 - k * CH - tloc) : (k * CH + tloc);
          f32x4 acc = {0.f, 0.f, 0.f, 0.f};
#pragma unroll
          for (int pass = 0; pass < 2; ++pass) {
            const __bf16* hsrc = A.h0 + ((size_t)t * BT + bL) * HROW + pass * 832;
            bf16x8 hreg[13];
#pragma unroll
            for (int i = 0; i < 12; ++i)
              hreg[i] = *(const bf16x8*)(hsrc + (i * 8 + w * 2 + gl) * 8);
            if (w < 2) hreg[12] = *(const bf16x8*)(hsrc + (96 + w * 2 + gl) * 8);
#pragma unroll
            for (int i = 0; i < 12; ++i)
              *(bf16x8*)(u2 + (size_t)(i * 8 + w * 2 + gl) * 256 + bL * 8) = hreg[i];
            if (w < 2)
              *(bf16x8*)(u2 + (size_t)(96 + w * 2 + gl) * 256 + bL * 8) = hreg[12];
            __syncthreads();
#pragma unroll
            for (int sl = 0; sl < 25; ++sl) {
              bf16x8 b = *(const bf16x8*)(wlds +
                  ((size_t)(rh * 50 + pass * 25 + sl) * 64 + l) * 8);
              bf16x8 a = *(const bf16x8*)(u2 +
                  (size_t)(sl * 4 + q) * 256 + (bh * 16 + nidx) * 8);
              acc = mfma16(a, b, acc);
            }
            __syncthreads();
          }
          union { u64 u; __bf16 h[4]; } pv;
#pragma unroll
          for (int r = 0; r < 4; ++r) pv.h[r] = (__bf16)(acc[r] + bn);
          ASTORE((u64*)(buf + ((size_t)(dir * CH + tloc) * 3200 + rr) * 32 +
                        bh * 16 + q * 4), pv.u);
        }
      }
      asm volatile("s_waitcnt vmcnt(0)" ::: "memory");   // xg at coherence pt
      __syncthreads();
      if (tid == 0) ASTORE(A.flags + (size_t)(100 + g) * 32, (unsigned)(k + 1));
    }
  }
}

// ---------------- FC + softmax + dihedral -> points ----------------
__global__ __launch_bounds__(256) void fc_kernel(
    const __bf16* __restrict__ h1, const __bf16* __restrict__ xpad,
    const __bf16* __restrict__ wfc, const float* __restrict__ fcb,
    const float* __restrict__ sinA, const float* __restrict__ cosA,
    float* __restrict__ pts) {
  __shared__ float lg[32 * 64];
  const int t = blockIdx.x, tid = threadIdx.x;
  const int wave = tid >> 6, lane = tid & 63, nidx = lane & 15, q = lane >> 4;
  const int a_col = wave * 16 + nidx;
  const __bf16* wrow = wfc + (size_t)a_col * 1664 + q * 8;
  const __bf16* h1row = h1 + (size_t)t * BT * HROW;
  const __bf16* xrow  = xpad + (size_t)t * BT * 64;
  f32x4 acc0 = {0.f, 0.f, 0.f, 0.f}, acc1 = {0.f, 0.f, 0.f, 0.f};
#pragma unroll
  for (int sl = 0; sl < 52; ++sl) {
    const int k = sl * 32 + q * 8;
    bf16x8 a0, a1;
    if (sl < 50) {
      const int kp = (sl < 25) ? k : (k + 32);
      a0 = *(const bf16x8*)(h1row + (size_t)nidx * HROW + kp);
      a1 = *(const bf16x8*)(h1row + (size_t)(16 + nidx) * HROW + kp);
    } else {
      a0 = *(const bf16x8*)(xrow + nidx * 64 + (k - 1600));
      a1 = *(const bf16x8*)(xrow + (16 + nidx) * 64 + (k - 1600));
    }
    bf16x8 bfr = *(const bf16x8*)(wrow + sl * 32);
    acc0 = mfma16(a0, bfr, acc0);
    acc1 = mfma16(a1, bfr, acc1);
  }
  const float bn = (a_col < 60) ? fcb[a_col] : -1e30f;
#pragma unroll
  for (int r = 0; r < 4; ++r) {
    lg[(q * 4 + r) * 64 + a_col]      = acc0[r] + bn;
    lg[(16 + q * 4 + r) * 64 + a_col] = acc1[r] + bn;
  }
  __syncthreads();

  const int b = tid >> 3, j = tid & 7;
  float v[8];
  float m = -1e30f;
#pragma unroll
  for (int k2 = 0; k2 < 8; ++k2) {
    v[k2] = lg[b * 64 + j + 8 * k2];
    m = fmaxf(m, v[k2]);
  }
  m = fmaxf(m, __shfl_xor(m, 1, 8));
  m = fmaxf(m, __shfl_xor(m, 2, 8));
  m = fmaxf(m, __shfl_xor(m, 4, 8));
  float s = 0.f;
#pragma unroll
  for (int k2 = 0; k2 < 8; ++k2) { v[k2] = __expf(v[k2] - m); s += v[k2]; }
  s += __shfl_xor(s, 1, 8);
  s += __shfl_xor(s, 2, 8);
  s += __shfl_xor(s, 4, 8);
  const float inv = 1.f / s;
  float ps[3] = {0.f, 0.f, 0.f}, pc[3] = {0.f, 0.f, 0.f};
#pragma unroll
  for (int k2 = 0; k2 < 8; ++k2) {
    const int a = j + 8 * k2;
    const float p = v[k2] * inv;
#pragma unroll
    for (int c = 0; c < 3; ++c) {
      ps[c] += p * sinA[a * 3 + c];
      pc[c] += p * cosA[a * 3 + c];
    }
  }
#pragma unroll
  for (int c = 0; c < 3; ++c) {
    ps[c] += __shfl_xor(ps[c], 1, 8);
    ps[c] += __shfl_xor(ps[c], 2, 8);
    ps[c] += __shfl_xor(ps[c], 4, 8);
    pc[c] += __shfl_xor(pc[c], 1, 8);
    pc[c] += __shfl_xor(pc[c], 2, 8);
    pc[c] += __shfl_xor(pc[c], 4, 8);
  }
  if (j == 0) {
    const float BL[3] = {145.801f, 152.326f, 132.868f};
    const float BA[3] = {2.124f, 1.941f, 2.028f};
#pragma unroll
    for (int c = 0; c < 3; ++c) {
      const float ang = 3.14159265358979323846f - BA[c];
      const float rct = BL[c] * cosf(ang), rst = BL[c] * sinf(ang);
      const float dih = atan2f(ps[c], pc[c]);
      float* o = pts + ((size_t)(3 * t + c) * BT + b) * 3;
      o[0] = rct;
      o[1] = cosf(dih) * rst;
      o[2] = sinf(dih) * rst;
    }
  }
}

// ---------------- sequential NeRF extension ----------------
__global__ void nerf_kernel(const float* __restrict__ pts, float* __restrict__ out) {
  const int b = threadIdx.x;
  if (b >= 32) return;
  float ax = -0.70710678f, ay = 1.22474487f, az = 0.f;
  float bx = -1.41421356f, by = 0.f, bz = 0.f;
  float cx = 0.f, cy = 0.f, cz = 0.f;
#pragma unroll 4
  for (int i = 0; i < 3 * TT; ++i) {
    const float* p = pts + ((size_t)i * BT + b) * 3;
    const float p0 = p[0], p1 = p[1], p2 = p[2];
    float ux = cx - bx, uy = cy - by, uz = cz - bz;
    const float ri = rsqrtf(ux * ux + uy * uy + uz * uz + 1e-12f);
    ux *= ri; uy *= ri; uz *= ri;
    const float wx = bx - ax, wy = by - ay, wz = bz - az;
    float nx = wy * uz - wz * uy, ny = wz * ux - wx * uz, nz = wx * uy - wy * ux;
    const float rn = rsqrtf(nx * nx + ny * ny + nz * nz + 1e-12f);
    nx *= rn; ny *= rn; nz *= rn;
    const float mx = ny * uz - nz * uy, my = nz * ux - nx * uz, mz = nx * uy - ny * ux;
    const float ox = cx + p0 * ux + p1 * mx + p2 * nx;
    const float oy = cy + p0 * uy + p1 * my + p2 * ny;
    const float oz = cz + p0 * uz + p1 * mz + p2 * nz;
    out[((size_t)i * BT + b) * 3 + 0] = ox;
    out[((size_t)i * BT + b) * 3 + 1] = oy;
    out[((size_t)i * BT + b) * 3 + 2] = oz;
    ax = bx; ay = by; az = bz;
    bx = cx; by = cy; bz = cz;
    cx = ox; cy = oy; cz = oz;
  }
}

// ---------------- launch ----------------
extern "C" void kernel_launch(void* const* d_in, const int* in_sizes, int n_in,
                              void* d_out, int out_size, void* d_ws, size_t ws_size,
                              hipStream_t stream) {
  (void)in_sizes; (void)n_in; (void)out_size;
  const int*   primary = (const int*)d_in[0];
  const float* evo     = (const float*)d_in[1];
  const float* emb     = (const float*)d_in[3];
  const float* Wih0f   = (const float*)d_in[4];
  const float* Whh0f   = (const float*)d_in[5];
  const float* b0f     = (const float*)d_in[6];
  const float* Wih0b   = (const float*)d_in[7];
  const float* Whh0b   = (const float*)d_in[8];
  const float* b0b     = (const float*)d_in[9];
  const float* Wih1f   = (const float*)d_in[10];
  const float* Whh1f   = (const float*)d_in[11];
  const float* b1f     = (const float*)d_in[12];
  const float* Wih1b   = (const float*)d_in[13];
  const float* Whh1b   = (const float*)d_in[14];
  const float* b1b     = (const float*)d_in[15];
  const float* fcW     = (const float*)d_in[16];
  const float* fcb     = (const float*)d_in[17];
  const float* alpha   = (const float*)d_in[18];

  char* ws = (char*)d_ws;
  size_t off = 0;
  auto take = [&](size_t n) -> void* {
    void* p = ws + off;
    off += (n + 511) & ~(size_t)511;
    return p;
  };
  __bf16* xpad = (__bf16*)take((size_t)TT * BT * 64 * 2);
  __bf16* zb   = (__bf16*)take((size_t)BT * HROW * 2);
  __bf16* wx0  = (__bf16*)take((size_t)2 * 3200 * 64 * 2);
  __bf16* wfc  = (__bf16*)take((size_t)64 * 1664 * 2);
  float*  sinA = (float*)take(192 * 4);
  float*  cosA = (float*)take(192 * 4);
  float*  pts  = (float*)take((size_t)3 * TT * BT * 3 * 4);
  u32*    flags0 = (u32*)take(11392 * 4);      // l0: 100 lines; l1: 256 lines
  u32*    flags1 = flags0 + 3200;
  __bf16* xg   = (__bf16*)take(2 * SLOT * 2);  // 41 MB, 2-slot ring
  __bf16* h0   = (__bf16*)take((size_t)TT * BT * HROW * 2);
  __bf16* h1   = (__bf16*)take((size_t)TT * BT * HROW * 2);
  if (off > ws_size) return;  // failure signature: absmax == max|ref| == 233472

  static int lds_cfg = 0;
  if (!lds_cfg) {
    hipFuncSetAttribute((const void*)lstm_l0,
                        hipFuncAttributeMaxDynamicSharedMemorySize, LDS_L0);
    hipFuncSetAttribute((const void*)lstm_l1,
                        hipFuncAttributeMaxDynamicSharedMemorySize, LDS_L1);
    lds_cfg = 1;
  }

  pack_wx0_kernel<<<1600, 256, 0, stream>>>(Wih0f, Wih0b, wx0);
  pack_fc_kernel<<<(64 * 1664 + 255) / 256, 256, 0, stream>>>(fcW, wfc);
  xpad_kernel<<<(TT * BT * 64) / 256, 256, 0, stream>>>(primary, evo, emb, xpad);
  small_init_kernel<<<209, 256, 0, stream>>>(zb, flags0, sinA, cosA, alpha);

  L0Args a0;
  a0.xpad = xpad; a0.wx0 = wx0; a0.zero = zb;
  a0.Whh0f = Whh0f; a0.Whh0b = Whh0b; a0.b0f = b0f; a0.b0b = b0b;
  a0.h0 = h0; a0.flags = flags0;
  lstm_l0<<<100, 256, LDS_L0, stream>>>(a0);

  L1Args a1;
  a1.h0 = h0; a1.zero = zb;
  a1.Whh1f = Whh1f; a1.Whh1b = Whh1b;
  a1.Wih1f = Wih1f; a1.Wih1b = Wih1b;
  a1.b1f = b1f; a1.b1b = b1b;
  a1.h1 = h1; a1.xg = xg; a1.flags = flags1;
  lstm_l1<<<256, 256, LDS_L1, stream>>>(a1);

  fc_kernel<<<TT, 256, 0, stream>>>(h1, xpad, wfc, fcb, sinA, cosA, pts);
  nerf_kernel<<<1, 64, 0, stream>>>(pts, (float*)d_out);
}